// Round 1
// baseline (414.160 us; speedup 1.0000x reference)
//
#include <hip/hip_runtime.h>
#include <hip/hip_bf16.h>

// Problem constants
#define B 4
#define N 1024
#define KNN 30
#define CIN 9
#define MM 8
#define OO 64
#define OUTC 512
#define HID 16
#define FD 320          // 5*64 concat feature dim
#define BNS 0.9999950000374997f   // 1/sqrt(1+1e-5)

// workspace float offsets
#define OFF_XT     0          // 36864
#define OFF_SQ     36864      // 4096
#define OFF_WT     40960      // 163840  (convt_w transposed: 320x512)
#define OFF_XYZ    204800     // 3440640 (B*N*K*28)
#define OFF_FEATS  3645440    // 1310720 (B*N*320)
#define OFF_SCORE  4956160    // 983040  (B*N*K*8)
#define OFF_POINT  5939200    // 2097152 (B*N*512)
#define OFF_CENTER 8036352    // 2097152
#define OFF_IDX    10133504   // 122880 ints

// ---------------- prep: transpose x -> xt, sq, zero out, transpose convt_w ----
__global__ void __launch_bounds__(256) k_prep(const float* __restrict__ x,
                                              const float* __restrict__ convt_w,
                                              float* __restrict__ xt,
                                              float* __restrict__ sq,
                                              float* __restrict__ wT,
                                              float* __restrict__ out) {
  int id = blockIdx.x * 256 + threadIdx.x;
  if (id < B * N) {
    int b = id >> 10, n = id & 1023;
    float s = 0.f;
#pragma unroll
    for (int c = 0; c < 9; c++) {
      float v = x[(b * 9 + c) * N + n];
      xt[id * 9 + c] = v;
      s = fmaf(v, v, s);
    }
    sq[id] = s;
  }
  if (id < B * OUTC) out[id] = 0.f;
  // convt_w (512,320) -> wT (320,512)
  if (id < 320 * 512) {
    int c = id >> 9, o = id & 511;
    wT[id] = convt_w[o * 320 + c];
  }
}

// ---------------- knn: one wave per row, top-30 via butterfly argmax ---------
__global__ void __launch_bounds__(256) k_knn(const float* __restrict__ xt,
                                             const float* __restrict__ sq,
                                             int* __restrict__ idx) {
  int row = blockIdx.x * 4 + (threadIdx.x >> 6);
  int lane = threadIdx.x & 63;
  int b = row >> 10;
  const float* xb = xt + (b << 10) * 9;
  const float* sb = sq + (b << 10);
  float cx[9];
#pragma unroll
  for (int c = 0; c < 9; c++) cx[c] = xt[row * 9 + c];
  float sqn = sq[row];
  float v[16];
  int mask = 0;
#pragma unroll
  for (int s = 0; s < 16; s++) {
    int j = s * 64 + lane;
    const float* xj = xb + j * 9;
    float dot = 0.f;
#pragma unroll
    for (int c = 0; c < 9; c++) dot = fmaf(cx[c], xj[c], dot);
    v[s] = 2.0f * dot - sqn - sb[j];   // exactly 0 for j==n (same fmaf order)
  }
  for (int r = 0; r < KNN; r++) {
    float best = -3.0e38f;
    int bj = 1 << 30;
#pragma unroll
    for (int s = 0; s < 16; s++) {
      if (!((mask >> s) & 1)) {
        float val = v[s];
        int j = s * 64 + lane;
        if (val > best || (val == best && j < bj)) { best = val; bj = j; }
      }
    }
#pragma unroll
    for (int d = 1; d < 64; d <<= 1) {
      float ov = __shfl_xor(best, d, 64);
      int oj = __shfl_xor(bj, d, 64);
      if (ov > best || (ov == best && oj < bj)) { best = ov; bj = oj; }
    }
    if (lane == 0) idx[row * KNN + r] = bj;
    if ((bj & 63) == lane) mask |= 1 << (bj >> 6);
  }
}

// ---------------- xyz build + conv1 + max_k -> x1 ---------------------------
__global__ void __launch_bounds__(64) k_xyzconv(const float* __restrict__ xt,
                                                const int* __restrict__ idx,
                                                const float* __restrict__ w,
                                                const float* __restrict__ bias,
                                                float* __restrict__ xyz,
                                                float* __restrict__ feats) {
  int row = blockIdx.x;   // b*N+n
  int t = threadIdx.x;    // 0..63
  int b = row >> 10;
  __shared__ float ws[64 * 18];
  __shared__ float diff_s[KNN][9];
  __shared__ float ctr_s[9];
  for (int i = t; i < 64 * 18; i += 64) ws[i] = w[i];
  if (t < 9) ctr_s[t] = xt[row * 9 + t];
  __syncthreads();
  if (t < KNN) {
    int j = idx[row * KNN + t];
    const float* xj = xt + ((b << 10) + j) * 9;
    float d2 = 0.f;
    float* xrow = xyz + (row * KNN + t) * 28;
#pragma unroll
    for (int c = 0; c < 9; c++) {
      float nb = xj[c], ct = ctr_s[c], df = nb - ct;
      diff_s[t][c] = df;
      xrow[c] = df; xrow[9 + c] = nb; xrow[18 + c] = ct;
      d2 = fmaf(df, df, d2);
    }
    xrow[27] = sqrtf(d2);
  }
  __syncthreads();
  // conv1: relu(bn(max)) monotonic -> max of diff-dot, ctr-dot constant over k
  float cd = 0.f;
#pragma unroll
  for (int c = 0; c < 9; c++) cd = fmaf(ctr_s[c], ws[t * 18 + 9 + c], cd);
  float best = -3.0e38f;
  for (int k = 0; k < KNN; k++) {
    float dd = 0.f;
#pragma unroll
    for (int c = 0; c < 9; c++) dd = fmaf(diff_s[k][c], ws[t * 18 + c], dd);
    best = fmaxf(best, dd);
  }
  float val = (best + cd + bias[t]) * BNS;
  feats[row * FD + t] = fmaxf(val, 0.f);
}

// ---------------- point/center GEMM: 16 points per block --------------------
__global__ void __launch_bounds__(256) k_pc(const float* __restrict__ feats,
                                            const float* __restrict__ mats,
                                            float* __restrict__ point,
                                            float* __restrict__ center, int l) {
  const float* kern = mats + l * 128 * 512;
  int g0 = blockIdx.x * 16;
  int t = threadIdx.x;
  __shared__ float fs[16][64];
  for (int i = t; i < 16 * 64; i += 256) {
    int p = i >> 6, k = i & 63;
    fs[p][k] = feats[(g0 + p) * FD + l * 64 + k];
  }
  __syncthreads();
  int c0 = t, c1 = t + 256;
  float aP0[16] = {}, aP1[16] = {}, aC0[16] = {}, aC1[16] = {};
  for (int k = 0; k < 64; k++) {
    float a0 = kern[k * 512 + c0], b0 = kern[(k + 64) * 512 + c0];
    float a1 = kern[k * 512 + c1], b1 = kern[(k + 64) * 512 + c1];
    float s0 = a0 + b0, s1 = a1 + b1;
#pragma unroll
    for (int p = 0; p < 16; p++) {
      float f = fs[p][k];
      aP0[p] = fmaf(f, s0, aP0[p]);
      aP1[p] = fmaf(f, s1, aP1[p]);
      aC0[p] = fmaf(f, a0, aC0[p]);
      aC1[p] = fmaf(f, a1, aC1[p]);
    }
  }
#pragma unroll
  for (int p = 0; p < 16; p++) {
    int base = (g0 + p) * 512;
    point[base + c0] = aP0[p];
    point[base + c1] = aP1[p];
    center[base + c0] = aC0[p];
    center[base + c1] = aC1[p];
  }
}

// ---------------- scorenet: per (b,n,k) thread ------------------------------
__global__ void __launch_bounds__(256) k_score(const float* __restrict__ xyz,
                                               const float* __restrict__ hw,
                                               const float* __restrict__ ow,
                                               const float* __restrict__ ob,
                                               float* __restrict__ score, int l) {
  __shared__ float hws[HID * 28], ows[MM * HID], obs[MM];
  int t = threadIdx.x;
  for (int i = t; i < HID * 28; i += 256) hws[i] = hw[l * HID * 28 + i];
  if (t < MM * HID) ows[t] = ow[l * MM * HID + t];
  if (t < MM) obs[t] = ob[l * MM + t];
  __syncthreads();
  int id = blockIdx.x * 256 + t;   // 0..B*N*K-1
  const float4* xr = (const float4*)(xyz + id * 28);
  float xv[28];
#pragma unroll
  for (int q = 0; q < 7; q++) {
    float4 f4 = xr[q];
    xv[q * 4] = f4.x; xv[q * 4 + 1] = f4.y; xv[q * 4 + 2] = f4.z; xv[q * 4 + 3] = f4.w;
  }
  float hid[HID];
#pragma unroll
  for (int h = 0; h < HID; h++) {
    float a = 0.f;
#pragma unroll
    for (int c = 0; c < 28; c++) a = fmaf(xv[c], hws[h * 28 + c], a);
    hid[h] = fmaxf(a * BNS, 0.f);
  }
  float lg[MM], mx = -3.0e38f;
#pragma unroll
  for (int m = 0; m < MM; m++) {
    float a = obs[m];
#pragma unroll
    for (int h = 0; h < HID; h++) a = fmaf(hid[h], ows[m * HID + h], a);
    lg[m] = a; mx = fmaxf(mx, a);
  }
  float ssum = 0.f;
#pragma unroll
  for (int m = 0; m < MM; m++) { lg[m] = __expf(lg[m] - mx); ssum += lg[m]; }
  float inv = 1.0f / ssum;
  float4* so = (float4*)(score + id * 8);
  so[0] = make_float4(lg[0] * inv, lg[1] * inv, lg[2] * inv, lg[3] * inv);
  so[1] = make_float4(lg[4] * inv, lg[5] * inv, lg[6] * inv, lg[7] * inv);
}

// ---------------- assemble: gather + weighted sum ---------------------------
__global__ void __launch_bounds__(64) k_asm(const float* __restrict__ score,
                                            const float* __restrict__ point,
                                            const float* __restrict__ center,
                                            const int* __restrict__ idx,
                                            float* __restrict__ feats, int l) {
  int row = blockIdx.x;   // b*N+n
  int t = threadIdx.x;    // o channel
  int b = row >> 10;
  __shared__ float sc[KNN][8];
  __shared__ int js[KNN];
  __shared__ float ssum[8];
  const float* srow = score + row * KNN * 8;
  for (int i = t; i < KNN * 8; i += 64) sc[i >> 3][i & 7] = srow[i];
  if (t < KNN) js[t] = (b << 10) + idx[row * KNN + t];
  __syncthreads();
  if (t < 8) {
    float a = 0.f;
#pragma unroll
    for (int k = 0; k < KNN; k++) a += sc[k][t];
    ssum[t] = a;
  }
  __syncthreads();
  float acc = 0.f;
  for (int k = 0; k < KNN; k++) {
    const float* pr = point + js[k] * 512 + t;
#pragma unroll
    for (int m = 0; m < 8; m++) acc = fmaf(sc[k][m], pr[m * 64], acc);
  }
  const float* cr = center + row * 512 + t;
#pragma unroll
  for (int m = 0; m < 8; m++) acc = fmaf(-ssum[m], cr[m * 64], acc);
  feats[row * FD + (l + 1) * 64 + t] = fmaxf(acc * BNS, 0.f);
}

// ---------------- final conv + global max pool ------------------------------
__global__ void __launch_bounds__(256) k_final(const float* __restrict__ feats,
                                               const float* __restrict__ wT,
                                               float* __restrict__ out) {
  int g0 = blockIdx.x * 16;
  int b = g0 >> 10;
  int t = threadIdx.x;
  __shared__ float xs[16 * FD];
  for (int i = t; i < 16 * FD; i += 256) xs[i] = feats[g0 * FD + i];
  __syncthreads();
  int c0 = t, c1 = t + 256;
  float a0[16] = {}, a1[16] = {};
  for (int k = 0; k < FD; k++) {
    float w0 = wT[k * 512 + c0], w1 = wT[k * 512 + c1];
#pragma unroll
    for (int p = 0; p < 16; p++) {
      float xv = xs[p * FD + k];
      a0[p] = fmaf(xv, w0, a0[p]);
      a1[p] = fmaf(xv, w1, a1[p]);
    }
  }
  float m0 = -3.0e38f, m1 = -3.0e38f;
#pragma unroll
  for (int p = 0; p < 16; p++) { m0 = fmaxf(m0, a0[p]); m1 = fmaxf(m1, a1[p]); }
  m0 = fmaxf(m0 * BNS, 0.f);   // relu(bn(max)) == max(relu(bn(.))) since BNS>0
  m1 = fmaxf(m1 * BNS, 0.f);
  atomicMax((unsigned int*)out + b * OUTC + c0, __float_as_uint(m0));
  atomicMax((unsigned int*)out + b * OUTC + c1, __float_as_uint(m1));
}

extern "C" void kernel_launch(void* const* d_in, const int* in_sizes, int n_in,
                              void* d_out, int out_size, void* d_ws, size_t ws_size,
                              hipStream_t stream) {
  const float* x       = (const float*)d_in[0];
  const float* conv1_w = (const float*)d_in[3];
  const float* conv1_b = (const float*)d_in[4];
  const float* sn_hw   = (const float*)d_in[5];
  const float* sn_ow   = (const float*)d_in[6];
  const float* sn_ob   = (const float*)d_in[7];
  const float* mats    = (const float*)d_in[8];
  const float* convt_w = (const float*)d_in[9];
  float* out = (float*)d_out;

  float* w      = (float*)d_ws;
  float* xt     = w + OFF_XT;
  float* sq     = w + OFF_SQ;
  float* wT     = w + OFF_WT;
  float* xyz    = w + OFF_XYZ;
  float* feats  = w + OFF_FEATS;
  float* score  = w + OFF_SCORE;
  float* point  = w + OFF_POINT;
  float* center = w + OFF_CENTER;
  int*   idx    = (int*)(w + OFF_IDX);

  k_prep<<<640, 256, 0, stream>>>(x, convt_w, xt, sq, wT, out);
  k_knn<<<1024, 256, 0, stream>>>(xt, sq, idx);
  k_xyzconv<<<4096, 64, 0, stream>>>(xt, idx, conv1_w, conv1_b, xyz, feats);
  for (int l = 0; l < 4; l++) {
    k_pc<<<256, 256, 0, stream>>>(feats, mats, point, center, l);
    k_score<<<480, 256, 0, stream>>>(xyz, sn_hw, sn_ow, sn_ob, score, l);
    k_asm<<<4096, 64, 0, stream>>>(score, point, center, idx, feats, l);
  }
  k_final<<<256, 256, 0, stream>>>(feats, wT, out);
}

// Round 2
// 396.165 us; speedup vs baseline: 1.0454x; 1.0454x over previous
//
#include <hip/hip_runtime.h>
#include <hip/hip_bf16.h>

// Problem constants
#define B 4
#define N 1024
#define KNN 30
#define CIN 9
#define MM 8
#define OO 64
#define OUTC 512
#define HID 16
#define FD 320          // 5*64 concat feature dim
#define BNS 0.9999950000374997f   // 1/sqrt(1+1e-5)

// workspace float offsets
#define OFF_XT     0          // 36864
#define OFF_SQ     36864      // 4096
#define OFF_WT     40960      // 163840  (convt_w transposed: 320x512)
#define OFF_XYZ    204800     // 3440640 (B*N*K*28)
#define OFF_FEATS  3645440    // 1310720 (B*N*320)
#define OFF_SCORE  4956160    // 983040  (B*N*K*8)
#define OFF_POINT  5939200    // 2097152 (B*N*512)
#define OFF_CENTER 8036352    // 2097152
#define OFF_IDX    10133504   // 122880 ints

// ---------------- prep: transpose x -> xt, sq, zero out, transpose convt_w ----
__global__ void __launch_bounds__(256) k_prep(const float* __restrict__ x,
                                              const float* __restrict__ convt_w,
                                              float* __restrict__ xt,
                                              float* __restrict__ sq,
                                              float* __restrict__ wT,
                                              float* __restrict__ out) {
  int id = blockIdx.x * 256 + threadIdx.x;
  if (id < B * N) {
    int b = id >> 10, n = id & 1023;
    float s = 0.f;
#pragma unroll
    for (int c = 0; c < 9; c++) {
      float v = x[(b * 9 + c) * N + n];
      xt[id * 9 + c] = v;
      s = fmaf(v, v, s);
    }
    sq[id] = s;
  }
  if (id < B * OUTC) out[id] = 0.f;
  // convt_w (512,320) -> wT (320,512)
  if (id < 320 * 512) {
    int c = id >> 9, o = id & 511;
    wT[id] = convt_w[o * 320 + c];
  }
}

// ---------------- knn: one wave per row, top-30 via butterfly argmax ---------
__global__ void __launch_bounds__(256) k_knn(const float* __restrict__ xt,
                                             const float* __restrict__ sq,
                                             int* __restrict__ idx) {
  int row = blockIdx.x * 4 + (threadIdx.x >> 6);
  int lane = threadIdx.x & 63;
  int b = row >> 10;
  const float* xb = xt + (b << 10) * 9;
  const float* sb = sq + (b << 10);
  float cx[9];
#pragma unroll
  for (int c = 0; c < 9; c++) cx[c] = xt[row * 9 + c];
  float sqn = sq[row];
  float v[16];
  int mask = 0;
#pragma unroll
  for (int s = 0; s < 16; s++) {
    int j = s * 64 + lane;
    const float* xj = xb + j * 9;
    float dot = 0.f;
#pragma unroll
    for (int c = 0; c < 9; c++) dot = fmaf(cx[c], xj[c], dot);
    v[s] = 2.0f * dot - sqn - sb[j];   // exactly 0 for j==n (same fmaf order)
  }
  for (int r = 0; r < KNN; r++) {
    float best = -3.0e38f;
    int bj = 1 << 30;
#pragma unroll
    for (int s = 0; s < 16; s++) {
      if (!((mask >> s) & 1)) {
        float val = v[s];
        int j = s * 64 + lane;
        if (val > best || (val == best && j < bj)) { best = val; bj = j; }
      }
    }
#pragma unroll
    for (int d = 1; d < 64; d <<= 1) {
      float ov = __shfl_xor(best, d, 64);
      int oj = __shfl_xor(bj, d, 64);
      if (ov > best || (ov == best && oj < bj)) { best = ov; bj = oj; }
    }
    if (lane == 0) idx[row * KNN + r] = bj;
    if ((bj & 63) == lane) mask |= 1 << (bj >> 6);
  }
}

// ---------------- xyz build + conv1 + max_k -> x1 ---------------------------
__global__ void __launch_bounds__(64) k_xyzconv(const float* __restrict__ xt,
                                                const int* __restrict__ idx,
                                                const float* __restrict__ w,
                                                const float* __restrict__ bias,
                                                float* __restrict__ xyz,
                                                float* __restrict__ feats) {
  int row = blockIdx.x;   // b*N+n
  int t = threadIdx.x;    // 0..63
  int b = row >> 10;
  __shared__ float ws[64 * 18];
  __shared__ __align__(16) float diff_s[KNN][12];
  __shared__ float ctr_s[9];
  for (int i = t; i < 64 * 18; i += 64) ws[i] = w[i];
  if (t < 9) ctr_s[t] = xt[row * 9 + t];
  __syncthreads();
  if (t < KNN) {
    int j = idx[row * KNN + t];
    const float* xj = xt + ((b << 10) + j) * 9;
    float d2 = 0.f;
    float* xrow = xyz + (row * KNN + t) * 28;
#pragma unroll
    for (int c = 0; c < 9; c++) {
      float nb = xj[c], ct = ctr_s[c], df = nb - ct;
      diff_s[t][c] = df;
      xrow[c] = df; xrow[9 + c] = nb; xrow[18 + c] = ct;
      d2 = fmaf(df, df, d2);
    }
    xrow[27] = sqrtf(d2);
  }
  __syncthreads();
  // hoist per-thread weights to registers
  float wd[9];
#pragma unroll
  for (int c = 0; c < 9; c++) wd[c] = ws[t * 18 + c];
  float cd = 0.f;
#pragma unroll
  for (int c = 0; c < 9; c++) cd = fmaf(ctr_s[c], ws[t * 18 + 9 + c], cd);
  float best = -3.0e38f;
  for (int k = 0; k < KNN; k++) {
    const float4* dr = (const float4*)diff_s[k];
    float4 d0 = dr[0], d1 = dr[1], d2v = dr[2];
    float dd = 0.f;
    dd = fmaf(d0.x, wd[0], dd); dd = fmaf(d0.y, wd[1], dd);
    dd = fmaf(d0.z, wd[2], dd); dd = fmaf(d0.w, wd[3], dd);
    dd = fmaf(d1.x, wd[4], dd); dd = fmaf(d1.y, wd[5], dd);
    dd = fmaf(d1.z, wd[6], dd); dd = fmaf(d1.w, wd[7], dd);
    dd = fmaf(d2v.x, wd[8], dd);
    best = fmaxf(best, dd);
  }
  float val = (best + cd + bias[t]) * BNS;
  feats[row * FD + t] = fmaxf(val, 0.f);
}

// ---------------- point/center GEMM: 16 points per block, 512 threads -------
__global__ void __launch_bounds__(512) k_pc(const float* __restrict__ feats,
                                            const float* __restrict__ mats,
                                            float* __restrict__ point,
                                            float* __restrict__ center, int l) {
  const float* kern = mats + l * 128 * 512;
  int g0 = blockIdx.x * 16;
  int t = threadIdx.x;     // channel 0..511
  __shared__ __align__(16) float fs[64][20];   // [k][p], padded rows (80B)
  for (int i = t; i < 16 * 64; i += 512) {
    int p = i >> 6, k = i & 63;
    fs[k][p] = feats[(g0 + p) * FD + l * 64 + k];
  }
  __syncthreads();
  float aP[16] = {}, aC[16] = {};
#pragma unroll 2
  for (int k = 0; k < 64; k++) {
    float a0 = kern[k * 512 + t];          // top half (center+point)
    float b0 = kern[(k + 64) * 512 + t];   // bottom half (point only)
    float s0 = a0 + b0;
    const float4* fr = (const float4*)fs[k];
    float4 f0 = fr[0], f1 = fr[1], f2 = fr[2], f3 = fr[3];
    float xv[16] = {f0.x, f0.y, f0.z, f0.w, f1.x, f1.y, f1.z, f1.w,
                    f2.x, f2.y, f2.z, f2.w, f3.x, f3.y, f3.z, f3.w};
#pragma unroll
    for (int p = 0; p < 16; p++) {
      aP[p] = fmaf(xv[p], s0, aP[p]);
      aC[p] = fmaf(xv[p], a0, aC[p]);
    }
  }
#pragma unroll
  for (int p = 0; p < 16; p++) {
    int base = (g0 + p) * 512 + t;
    point[base] = aP[p];
    center[base] = aC[p];
  }
}

// ---------------- scorenet: per (b,n,k) thread ------------------------------
__global__ void __launch_bounds__(256) k_score(const float* __restrict__ xyz,
                                               const float* __restrict__ hw,
                                               const float* __restrict__ ow,
                                               const float* __restrict__ ob,
                                               float* __restrict__ score, int l) {
  __shared__ float hws[HID * 28], ows[MM * HID], obs[MM];
  int t = threadIdx.x;
  for (int i = t; i < HID * 28; i += 256) hws[i] = hw[l * HID * 28 + i];
  if (t < MM * HID) ows[t] = ow[l * MM * HID + t];
  if (t < MM) obs[t] = ob[l * MM + t];
  __syncthreads();
  int id = blockIdx.x * 256 + t;   // 0..B*N*K-1
  const float4* xr = (const float4*)(xyz + id * 28);
  float xv[28];
#pragma unroll
  for (int q = 0; q < 7; q++) {
    float4 f4 = xr[q];
    xv[q * 4] = f4.x; xv[q * 4 + 1] = f4.y; xv[q * 4 + 2] = f4.z; xv[q * 4 + 3] = f4.w;
  }
  float hid[HID];
#pragma unroll
  for (int h = 0; h < HID; h++) {
    float a = 0.f;
#pragma unroll
    for (int c = 0; c < 28; c++) a = fmaf(xv[c], hws[h * 28 + c], a);
    hid[h] = fmaxf(a * BNS, 0.f);
  }
  float lg[MM], mx = -3.0e38f;
#pragma unroll
  for (int m = 0; m < MM; m++) {
    float a = obs[m];
#pragma unroll
    for (int h = 0; h < HID; h++) a = fmaf(hid[h], ows[m * HID + h], a);
    lg[m] = a; mx = fmaxf(mx, a);
  }
  float ssum = 0.f;
#pragma unroll
  for (int m = 0; m < MM; m++) { lg[m] = __expf(lg[m] - mx); ssum += lg[m]; }
  float inv = 1.0f / ssum;
  float4* so = (float4*)(score + id * 8);
  so[0] = make_float4(lg[0] * inv, lg[1] * inv, lg[2] * inv, lg[3] * inv);
  so[1] = make_float4(lg[4] * inv, lg[5] * inv, lg[6] * inv, lg[7] * inv);
}

// ---------------- assemble: gather + weighted sum ---------------------------
__global__ void __launch_bounds__(64) k_asm(const float* __restrict__ score,
                                            const float* __restrict__ point,
                                            const float* __restrict__ center,
                                            const int* __restrict__ idx,
                                            float* __restrict__ feats, int l) {
  int row = blockIdx.x;   // b*N+n
  int t = threadIdx.x;    // o channel
  int b = row >> 10;
  __shared__ float sc[KNN][8];
  __shared__ int js[KNN];
  __shared__ float ssum[8];
  const float* srow = score + row * KNN * 8;
  for (int i = t; i < KNN * 8; i += 64) sc[i >> 3][i & 7] = srow[i];
  if (t < KNN) js[t] = ((b << 10) + idx[row * KNN + t]) * 512;
  __syncthreads();
  if (t < 8) {
    float a = 0.f;
#pragma unroll
    for (int k = 0; k < KNN; k++) a += sc[k][t];
    ssum[t] = a;
  }
  __syncthreads();
  float acc = 0.f;
#pragma unroll 2
  for (int k = 0; k < KNN; k++) {
    const float* pr = point + js[k] + t;
#pragma unroll
    for (int m = 0; m < 8; m++) acc = fmaf(sc[k][m], pr[m * 64], acc);
  }
  const float* cr = center + row * 512 + t;
#pragma unroll
  for (int m = 0; m < 8; m++) acc = fmaf(-ssum[m], cr[m * 64], acc);
  feats[row * FD + (l + 1) * 64 + t] = fmaxf(acc * BNS, 0.f);
}

// ---------------- final conv + global max pool ------------------------------
__global__ void __launch_bounds__(512) k_final(const float* __restrict__ feats,
                                               const float* __restrict__ wT,
                                               float* __restrict__ out) {
  int g0 = blockIdx.x * 16;
  int b = g0 >> 10;
  int t = threadIdx.x;   // channel 0..511
  __shared__ __align__(16) float xs[320][20];  // [k][p], padded rows (80B)
  for (int i = t; i < 16 * 320; i += 512) {
    int p = i / 320, k = i - p * 320;
    xs[k][p] = feats[(g0 + p) * FD + k];
  }
  __syncthreads();
  float a[16] = {};
#pragma unroll 2
  for (int k = 0; k < 320; k++) {
    float w0 = wT[k * 512 + t];
    const float4* fr = (const float4*)xs[k];
    float4 f0 = fr[0], f1 = fr[1], f2 = fr[2], f3 = fr[3];
    float xv[16] = {f0.x, f0.y, f0.z, f0.w, f1.x, f1.y, f1.z, f1.w,
                    f2.x, f2.y, f2.z, f2.w, f3.x, f3.y, f3.z, f3.w};
#pragma unroll
    for (int p = 0; p < 16; p++) a[p] = fmaf(xv[p], w0, a[p]);
  }
  float m0 = -3.0e38f;
#pragma unroll
  for (int p = 0; p < 16; p++) m0 = fmaxf(m0, a[p]);
  m0 = fmaxf(m0 * BNS, 0.f);   // relu(bn(max)) == max(relu(bn(.))) since BNS>0
  atomicMax((unsigned int*)out + b * OUTC + t, __float_as_uint(m0));
}

extern "C" void kernel_launch(void* const* d_in, const int* in_sizes, int n_in,
                              void* d_out, int out_size, void* d_ws, size_t ws_size,
                              hipStream_t stream) {
  const float* x       = (const float*)d_in[0];
  const float* conv1_w = (const float*)d_in[3];
  const float* conv1_b = (const float*)d_in[4];
  const float* sn_hw   = (const float*)d_in[5];
  const float* sn_ow   = (const float*)d_in[6];
  const float* sn_ob   = (const float*)d_in[7];
  const float* mats    = (const float*)d_in[8];
  const float* convt_w = (const float*)d_in[9];
  float* out = (float*)d_out;

  float* w      = (float*)d_ws;
  float* xt     = w + OFF_XT;
  float* sq     = w + OFF_SQ;
  float* wT     = w + OFF_WT;
  float* xyz    = w + OFF_XYZ;
  float* feats  = w + OFF_FEATS;
  float* score  = w + OFF_SCORE;
  float* point  = w + OFF_POINT;
  float* center = w + OFF_CENTER;
  int*   idx    = (int*)(w + OFF_IDX);

  k_prep<<<640, 256, 0, stream>>>(x, convt_w, xt, sq, wT, out);
  k_knn<<<1024, 256, 0, stream>>>(xt, sq, idx);
  k_xyzconv<<<4096, 64, 0, stream>>>(xt, idx, conv1_w, conv1_b, xyz, feats);
  for (int l = 0; l < 4; l++) {
    k_pc<<<256, 512, 0, stream>>>(feats, mats, point, center, l);
    k_score<<<480, 256, 0, stream>>>(xyz, sn_hw, sn_ow, sn_ob, score, l);
    k_asm<<<4096, 64, 0, stream>>>(score, point, center, idx, feats, l);
  }
  k_final<<<256, 512, 0, stream>>>(feats, wT, out);
}

// Round 3
// 353.622 us; speedup vs baseline: 1.1712x; 1.1203x over previous
//
#include <hip/hip_runtime.h>
#include <hip/hip_bf16.h>

// Problem constants
#define B 4
#define N 1024
#define KNN 30
#define CIN 9
#define MM 8
#define OO 64
#define OUTC 512
#define HID 16
#define FD 320          // 5*64 concat feature dim
#define BNS 0.9999950000374997f   // 1/sqrt(1+1e-5)

// workspace float offsets
#define OFF_XT     0          // 36864
#define OFF_SQ     36864      // 4096
#define OFF_WT     40960      // 163840  (convt_w transposed: 320x512)
#define OFF_FEATS  3645440    // 1310720 (B*N*320)
#define OFF_POINT  5939200    // 2097152 (B*N*512)
#define OFF_CENTER 8036352    // 2097152
#define OFF_IDX    10133504   // 122880 ints

// ---------------- prep: transpose x -> xt, sq, zero out, transpose convt_w ----
__global__ void __launch_bounds__(256) k_prep(const float* __restrict__ x,
                                              const float* __restrict__ convt_w,
                                              float* __restrict__ xt,
                                              float* __restrict__ sq,
                                              float* __restrict__ wT,
                                              float* __restrict__ out) {
  int id = blockIdx.x * 256 + threadIdx.x;
  if (id < B * N) {
    int b = id >> 10, n = id & 1023;
    float s = 0.f;
#pragma unroll
    for (int c = 0; c < 9; c++) {
      float v = x[(b * 9 + c) * N + n];
      xt[id * 9 + c] = v;
      s = fmaf(v, v, s);
    }
    sq[id] = s;
  }
  if (id < B * OUTC) out[id] = 0.f;
  // convt_w (512,320) -> wT (320,512)
  if (id < 320 * 512) {
    int c = id >> 9, o = id & 511;
    wT[id] = convt_w[o * 320 + c];
  }
}

// ---------------- knn: per-lane sorted-16 + head-pointer selection ----------
__global__ void __launch_bounds__(256) k_knn(const float* __restrict__ xt,
                                             const float* __restrict__ sq,
                                             int* __restrict__ idx) {
  int row = blockIdx.x * 4 + (threadIdx.x >> 6);
  int lane = threadIdx.x & 63;
  int b = row >> 10;
  const float* xb = xt + (b << 10) * 9;
  const float* sb = sq + (b << 10);
  float cx[9];
#pragma unroll
  for (int c = 0; c < 9; c++) cx[c] = xt[row * 9 + c];
  float sqn = sq[row];
  float sv[16];
  int sj[16];
#pragma unroll
  for (int s = 0; s < 16; s++) {
    int j = s * 64 + lane;
    const float* xj = xb + j * 9;
    float dot = 0.f;
#pragma unroll
    for (int c = 0; c < 9; c++) dot = fmaf(cx[c], xj[c], dot);
    sv[s] = 2.0f * dot - sqn - sb[j];   // exactly 0 for j==n (same fmaf order)
    sj[s] = j;
  }
  // sort 16 descending by (v desc, j asc): Batcher odd-even mergesort, 63 CEs
#define CE(a, b) { bool sw = (sv[b] > sv[a]) || (sv[b] == sv[a] && sj[b] < sj[a]); \
    float tv = sw ? sv[b] : sv[a]; sv[b] = sw ? sv[a] : sv[b]; sv[a] = tv;         \
    int   tj = sw ? sj[b] : sj[a]; sj[b] = sw ? sj[a] : sj[b]; sj[a] = tj; }
  CE(0,1) CE(2,3) CE(4,5) CE(6,7) CE(8,9) CE(10,11) CE(12,13) CE(14,15)
  CE(0,2) CE(1,3) CE(4,6) CE(5,7) CE(8,10) CE(9,11) CE(12,14) CE(13,15)
  CE(1,2) CE(5,6) CE(9,10) CE(13,14)
  CE(0,4) CE(1,5) CE(2,6) CE(3,7) CE(8,12) CE(9,13) CE(10,14) CE(11,15)
  CE(2,4) CE(3,5) CE(10,12) CE(11,13)
  CE(1,2) CE(3,4) CE(5,6) CE(9,10) CE(11,12) CE(13,14)
  CE(0,8) CE(1,9) CE(2,10) CE(3,11) CE(4,12) CE(5,13) CE(6,14) CE(7,15)
  CE(4,8) CE(5,9) CE(6,10) CE(7,11)
  CE(2,4) CE(3,5) CE(6,8) CE(7,9) CE(10,12) CE(11,13)
  CE(1,2) CE(3,4) CE(5,6) CE(7,8) CE(9,10) CE(11,12) CE(13,14)
#undef CE
  // selection: butterfly-max over per-lane heads, winner shifts its list
  for (int r = 0; r < KNN; r++) {
    float wv = sv[0];
    int wj = sj[0];
#pragma unroll
    for (int d = 1; d < 64; d <<= 1) {
      float ov = __shfl_xor(wv, d, 64);
      int oj = __shfl_xor(wj, d, 64);
      if (ov > wv || (ov == wv && oj < wj)) { wv = ov; wj = oj; }
    }
    if (lane == 0) idx[row * KNN + r] = wj;
    bool adv = (sv[0] == wv) && (sj[0] == wj);
#pragma unroll
    for (int i = 0; i < 15; i++) {
      sv[i] = adv ? sv[i + 1] : sv[i];
      sj[i] = adv ? sj[i + 1] : sj[i];
    }
    sv[15] = adv ? -3.0e38f : sv[15];
    sj[15] = adv ? 0x7fffffff : sj[15];
  }
}

// ---------------- conv1 + max_k -> x1 (first 64 feat channels) --------------
__global__ void __launch_bounds__(64) k_conv1(const float* __restrict__ xt,
                                              const int* __restrict__ idx,
                                              const float* __restrict__ w,
                                              const float* __restrict__ bias,
                                              float* __restrict__ feats) {
  int row = blockIdx.x;   // b*N+n
  int t = threadIdx.x;    // 0..63
  int b = row >> 10;
  __shared__ float ws[64 * 18];
  __shared__ __align__(16) float diff_s[KNN][12];
  __shared__ float ctr_s[9];
  for (int i = t; i < 64 * 18; i += 64) ws[i] = w[i];
  if (t < 9) ctr_s[t] = xt[row * 9 + t];
  __syncthreads();
  if (t < KNN) {
    int j = idx[row * KNN + t];
    const float* xj = xt + ((b << 10) + j) * 9;
#pragma unroll
    for (int c = 0; c < 9; c++) diff_s[t][c] = xj[c] - ctr_s[c];
  }
  __syncthreads();
  float wd[9];
#pragma unroll
  for (int c = 0; c < 9; c++) wd[c] = ws[t * 18 + c];
  float cd = 0.f;
#pragma unroll
  for (int c = 0; c < 9; c++) cd = fmaf(ctr_s[c], ws[t * 18 + 9 + c], cd);
  float best = -3.0e38f;
  for (int k = 0; k < KNN; k++) {
    const float4* dr = (const float4*)diff_s[k];
    float4 d0 = dr[0], d1 = dr[1], d2v = dr[2];
    float dd = 0.f;
    dd = fmaf(d0.x, wd[0], dd); dd = fmaf(d0.y, wd[1], dd);
    dd = fmaf(d0.z, wd[2], dd); dd = fmaf(d0.w, wd[3], dd);
    dd = fmaf(d1.x, wd[4], dd); dd = fmaf(d1.y, wd[5], dd);
    dd = fmaf(d1.z, wd[6], dd); dd = fmaf(d1.w, wd[7], dd);
    dd = fmaf(d2v.x, wd[8], dd);
    best = fmaxf(best, dd);
  }
  float val = (best + cd + bias[t]) * BNS;
  feats[row * FD + t] = fmaxf(val, 0.f);
}

// ---------------- point/center GEMM: 16 points per block, 512 threads -------
__global__ void __launch_bounds__(512) k_pc(const float* __restrict__ feats,
                                            const float* __restrict__ mats,
                                            float* __restrict__ point,
                                            float* __restrict__ center, int l) {
  const float* kern = mats + l * 128 * 512;
  int g0 = blockIdx.x * 16;
  int t = threadIdx.x;     // channel 0..511
  __shared__ __align__(16) float fs[64][20];   // [k][p], padded rows (80B)
  for (int i = t; i < 16 * 64; i += 512) {
    int p = i >> 6, k = i & 63;
    fs[k][p] = feats[(g0 + p) * FD + l * 64 + k];
  }
  __syncthreads();
  float aP[16] = {}, aC[16] = {};
#pragma unroll 2
  for (int k = 0; k < 64; k++) {
    float a0 = kern[k * 512 + t];          // top half (center+point)
    float b0 = kern[(k + 64) * 512 + t];   // bottom half (point only)
    float s0 = a0 + b0;
    const float4* fr = (const float4*)fs[k];
    float4 f0 = fr[0], f1 = fr[1], f2 = fr[2], f3 = fr[3];
    float xv[16] = {f0.x, f0.y, f0.z, f0.w, f1.x, f1.y, f1.z, f1.w,
                    f2.x, f2.y, f2.z, f2.w, f3.x, f3.y, f3.z, f3.w};
#pragma unroll
    for (int p = 0; p < 16; p++) {
      aP[p] = fmaf(xv[p], s0, aP[p]);
      aC[p] = fmaf(xv[p], a0, aC[p]);
    }
  }
#pragma unroll
  for (int p = 0; p < 16; p++) {
    int base = (g0 + p) * 512 + t;
    point[base] = aP[p];
    center[base] = aC[p];
  }
}

// ---------------- fused scorenet + assemble: 4 rows per 256-thread block ----
__global__ void __launch_bounds__(256) k_asm2(const float* __restrict__ xt,
                                              const int* __restrict__ idx,
                                              const float* __restrict__ hw,
                                              const float* __restrict__ ow,
                                              const float* __restrict__ ob,
                                              const float* __restrict__ point,
                                              const float* __restrict__ center,
                                              float* __restrict__ feats, int l) {
  int row0 = blockIdx.x * 4;
  int t = threadIdx.x;
  int b = row0 >> 10;
  __shared__ float hws[HID * 28];
  __shared__ float ows[MM * HID];
  __shared__ float obs[MM];
  __shared__ __align__(16) float sc[4][KNN][8];
  __shared__ __align__(16) float ssum[4][8];
  __shared__ int js[4][KNN];
  __shared__ float ctr[4][9];
  for (int i = t; i < HID * 28; i += 256) hws[i] = hw[l * HID * 28 + i];
  if (t < MM * HID) ows[t] = ow[l * MM * HID + t];
  if (t < MM) obs[t] = ob[l * MM + t];
  if (t < 36) { int r = t / 9, c = t - r * 9; ctr[r][c] = xt[(row0 + r) * 9 + c]; }
  if (t < 4 * KNN) {
    int r = t / KNN, k = t - r * KNN;
    js[r][k] = (b << 10) + idx[(row0 + r) * KNN + k];
  }
  __syncthreads();
  if (t < 4 * KNN) {
    int r = t / KNN, k = t - r * KNN;
    const float* xj = xt + js[r][k] * 9;
    float xv[28];
    float d2 = 0.f;
#pragma unroll
    for (int c = 0; c < 9; c++) {
      float nb = xj[c], ct = ctr[r][c], df = nb - ct;
      xv[c] = df; xv[9 + c] = nb; xv[18 + c] = ct;
      d2 = fmaf(df, df, d2);
    }
    xv[27] = sqrtf(d2);
    float hid[HID];
#pragma unroll
    for (int h = 0; h < HID; h++) {
      float a = 0.f;
#pragma unroll
      for (int c = 0; c < 28; c++) a = fmaf(xv[c], hws[h * 28 + c], a);
      hid[h] = fmaxf(a * BNS, 0.f);
    }
    float lg[MM], mx = -3.0e38f;
#pragma unroll
    for (int m = 0; m < MM; m++) {
      float a = obs[m];
#pragma unroll
      for (int h = 0; h < HID; h++) a = fmaf(hid[h], ows[m * HID + h], a);
      lg[m] = a; mx = fmaxf(mx, a);
    }
    float s = 0.f;
#pragma unroll
    for (int m = 0; m < MM; m++) { lg[m] = __expf(lg[m] - mx); s += lg[m]; }
    float inv = 1.0f / s;
#pragma unroll
    for (int m = 0; m < MM; m++) sc[r][k][m] = lg[m] * inv;
  }
  __syncthreads();
  if (t < 32) {
    int r = t >> 3, m = t & 7;
    float a = 0.f;
#pragma unroll
    for (int k = 0; k < KNN; k++) a += sc[r][k][m];
    ssum[r][m] = a;
  }
  __syncthreads();
  int r = t >> 6, lane = t & 63;
  int row = row0 + r;
  float acc = 0.f;
#pragma unroll 2
  for (int k = 0; k < KNN; k++) {
    const float4* s4 = (const float4*)sc[r][k];
    float4 s0 = s4[0], s1 = s4[1];
    const float* pr = point + (js[r][k] << 9) + lane;
    acc = fmaf(s0.x, pr[0], acc);
    acc = fmaf(s0.y, pr[64], acc);
    acc = fmaf(s0.z, pr[128], acc);
    acc = fmaf(s0.w, pr[192], acc);
    acc = fmaf(s1.x, pr[256], acc);
    acc = fmaf(s1.y, pr[320], acc);
    acc = fmaf(s1.z, pr[384], acc);
    acc = fmaf(s1.w, pr[448], acc);
  }
  const float4* u4 = (const float4*)ssum[r];
  float4 u0 = u4[0], u1 = u4[1];
  const float* cr = center + (row << 9) + lane;
  acc = fmaf(-u0.x, cr[0], acc);
  acc = fmaf(-u0.y, cr[64], acc);
  acc = fmaf(-u0.z, cr[128], acc);
  acc = fmaf(-u0.w, cr[192], acc);
  acc = fmaf(-u1.x, cr[256], acc);
  acc = fmaf(-u1.y, cr[320], acc);
  acc = fmaf(-u1.z, cr[384], acc);
  acc = fmaf(-u1.w, cr[448], acc);
  feats[row * FD + (l + 1) * 64 + lane] = fmaxf(acc * BNS, 0.f);
}

// ---------------- final conv + global max pool ------------------------------
__global__ void __launch_bounds__(512) k_final(const float* __restrict__ feats,
                                               const float* __restrict__ wT,
                                               float* __restrict__ out) {
  int g0 = blockIdx.x * 16;
  int b = g0 >> 10;
  int t = threadIdx.x;   // channel 0..511
  __shared__ __align__(16) float xs[320][20];  // [k][p], padded rows (80B)
  for (int i = t; i < 16 * 320; i += 512) {
    int p = i / 320, k = i - p * 320;
    xs[k][p] = feats[(g0 + p) * FD + k];
  }
  __syncthreads();
  float a[16] = {};
#pragma unroll 2
  for (int k = 0; k < 320; k++) {
    float w0 = wT[k * 512 + t];
    const float4* fr = (const float4*)xs[k];
    float4 f0 = fr[0], f1 = fr[1], f2 = fr[2], f3 = fr[3];
    float xv[16] = {f0.x, f0.y, f0.z, f0.w, f1.x, f1.y, f1.z, f1.w,
                    f2.x, f2.y, f2.z, f2.w, f3.x, f3.y, f3.z, f3.w};
#pragma unroll
    for (int p = 0; p < 16; p++) a[p] = fmaf(xv[p], w0, a[p]);
  }
  float m0 = -3.0e38f;
#pragma unroll
  for (int p = 0; p < 16; p++) m0 = fmaxf(m0, a[p]);
  m0 = fmaxf(m0 * BNS, 0.f);   // relu(bn(max)) == max(relu(bn(.))) since BNS>0
  atomicMax((unsigned int*)out + b * OUTC + t, __float_as_uint(m0));
}

extern "C" void kernel_launch(void* const* d_in, const int* in_sizes, int n_in,
                              void* d_out, int out_size, void* d_ws, size_t ws_size,
                              hipStream_t stream) {
  const float* x       = (const float*)d_in[0];
  const float* conv1_w = (const float*)d_in[3];
  const float* conv1_b = (const float*)d_in[4];
  const float* sn_hw   = (const float*)d_in[5];
  const float* sn_ow   = (const float*)d_in[6];
  const float* sn_ob   = (const float*)d_in[7];
  const float* mats    = (const float*)d_in[8];
  const float* convt_w = (const float*)d_in[9];
  float* out = (float*)d_out;

  float* w      = (float*)d_ws;
  float* xt     = w + OFF_XT;
  float* sq     = w + OFF_SQ;
  float* wT     = w + OFF_WT;
  float* feats  = w + OFF_FEATS;
  float* point  = w + OFF_POINT;
  float* center = w + OFF_CENTER;
  int*   idx    = (int*)(w + OFF_IDX);

  k_prep<<<640, 256, 0, stream>>>(x, convt_w, xt, sq, wT, out);
  k_knn<<<1024, 256, 0, stream>>>(xt, sq, idx);
  k_conv1<<<4096, 64, 0, stream>>>(xt, idx, conv1_w, conv1_b, feats);
  for (int l = 0; l < 4; l++) {
    k_pc<<<256, 512, 0, stream>>>(feats, mats, point, center, l);
    k_asm2<<<1024, 256, 0, stream>>>(xt, idx, sn_hw, sn_ow, sn_ob, point, center, feats, l);
  }
  k_final<<<256, 512, 0, stream>>>(feats, wT, out);
}

// Round 5
// 234.798 us; speedup vs baseline: 1.7639x; 1.5061x over previous
//
#include <hip/hip_runtime.h>
#include <hip/hip_bf16.h>

// Problem constants
#define B 4
#define N 1024
#define KNN 30
#define MM 8
#define OO 64
#define OUTC 512
#define HID 16
#define FD 320
#define BNS 0.9999950000374997f   // 1/sqrt(1+1e-5)

typedef float f32x4 __attribute__((ext_vector_type(4)));
typedef short s16x8 __attribute__((ext_vector_type(8)));

// workspace float offsets
#define OFF_XT     0          // 36864 floats
#define OFF_SQ     36864      // 4096
#define OFF_IDX    40960      // 122880 ints
#define OFF_CVT    163840     // convt bf16: 512*320 = 163840 bf16 = 81920 floats
#define OFF_K2T    245760     // 4*64*1024 bf16 = 262144 bf16 = 131072 floats
#define OFF_FB     376832     // feats bf16: 4096*320 = 1310720 bf16 = 655360 floats
#define OFF_H      1032192    // H bf16: 4096*1024 = 4194304 bf16 = 2097152 floats
// total 3129344 floats = 12.5 MB

// ---------------- prep: xt/sq, zero out, bf16 conversions -------------------
__global__ void __launch_bounds__(256) k_prep(const float* __restrict__ x,
                                              const float* __restrict__ convt_w,
                                              const float* __restrict__ mats,
                                              float* __restrict__ xt,
                                              float* __restrict__ sq,
                                              __hip_bfloat16* __restrict__ cvt_bf,
                                              __hip_bfloat16* __restrict__ k2t_bf,
                                              float* __restrict__ out) {
  int id = blockIdx.x * 256 + threadIdx.x;   // grid 1024*256 = 262144
  if (id < B * N) {
    int b = id >> 10, n = id & 1023;
    float s = 0.f;
#pragma unroll
    for (int c = 0; c < 9; c++) {
      float v = x[(b * 9 + c) * N + n];
      xt[id * 9 + c] = v;
      s = fmaf(v, v, s);
    }
    sq[id] = s;
  }
  if (id < B * OUTC) out[id] = 0.f;
  if (id < 512 * 320) cvt_bf[id] = __float2bfloat16(convt_w[id]);
  // K2T[l][o][kap]: kap = part*512 + m*64 + c -> mats[l][part*64+c][m*64+o]
  {
    int l = id >> 16, rem = id & 65535;
    int o = rem >> 10, kap = rem & 1023;
    int part = kap >> 9, mc = kap & 511;
    int m = mc >> 6, c = mc & 63;
    k2t_bf[id] = __float2bfloat16(mats[l * 65536 + (part * 64 + c) * 512 + m * 64 + o]);
  }
}

// ---------------- knn: per-lane sorted-16 + head-pointer selection ----------
__global__ void __launch_bounds__(256) k_knn(const float* __restrict__ xt,
                                             const float* __restrict__ sq,
                                             int* __restrict__ idx) {
  int row = blockIdx.x * 4 + (threadIdx.x >> 6);
  int lane = threadIdx.x & 63;
  int b = row >> 10;
  const float* xb = xt + (b << 10) * 9;
  const float* sb = sq + (b << 10);
  float cx[9];
#pragma unroll
  for (int c = 0; c < 9; c++) cx[c] = xt[row * 9 + c];
  float sqn = sq[row];
  float sv[16];
  int sj[16];
#pragma unroll
  for (int s = 0; s < 16; s++) {
    int j = s * 64 + lane;
    const float* xj = xb + j * 9;
    float dot = 0.f;
#pragma unroll
    for (int c = 0; c < 9; c++) dot = fmaf(cx[c], xj[c], dot);
    sv[s] = 2.0f * dot - sqn - sb[j];
    sj[s] = j;
  }
#define CE(a, b) { bool sw = (sv[b] > sv[a]) || (sv[b] == sv[a] && sj[b] < sj[a]); \
    float tv = sw ? sv[b] : sv[a]; sv[b] = sw ? sv[a] : sv[b]; sv[a] = tv;         \
    int   tj = sw ? sj[b] : sj[a]; sj[b] = sw ? sj[a] : sj[b]; sj[a] = tj; }
  CE(0,1) CE(2,3) CE(4,5) CE(6,7) CE(8,9) CE(10,11) CE(12,13) CE(14,15)
  CE(0,2) CE(1,3) CE(4,6) CE(5,7) CE(8,10) CE(9,11) CE(12,14) CE(13,15)
  CE(1,2) CE(5,6) CE(9,10) CE(13,14)
  CE(0,4) CE(1,5) CE(2,6) CE(3,7) CE(8,12) CE(9,13) CE(10,14) CE(11,15)
  CE(2,4) CE(3,5) CE(10,12) CE(11,13)
  CE(1,2) CE(3,4) CE(5,6) CE(9,10) CE(11,12) CE(13,14)
  CE(0,8) CE(1,9) CE(2,10) CE(3,11) CE(4,12) CE(5,13) CE(6,14) CE(7,15)
  CE(4,8) CE(5,9) CE(6,10) CE(7,11)
  CE(2,4) CE(3,5) CE(6,8) CE(7,9) CE(10,12) CE(11,13)
  CE(1,2) CE(3,4) CE(5,6) CE(7,8) CE(9,10) CE(11,12) CE(13,14)
#undef CE
  for (int r = 0; r < KNN; r++) {
    float wv = sv[0];
    int wj = sj[0];
#pragma unroll
    for (int d = 1; d < 64; d <<= 1) {
      float ov = __shfl_xor(wv, d, 64);
      int oj = __shfl_xor(wj, d, 64);
      if (ov > wv || (ov == wv && oj < wj)) { wv = ov; wj = oj; }
    }
    if (lane == 0) idx[row * KNN + r] = wj;
    bool adv = (sv[0] == wv) && (sj[0] == wj);
#pragma unroll
    for (int i = 0; i < 15; i++) {
      sv[i] = adv ? sv[i + 1] : sv[i];
      sj[i] = adv ? sj[i + 1] : sj[i];
    }
    sv[15] = adv ? -3.0e38f : sv[15];
    sj[15] = adv ? 0x7fffffff : sj[15];
  }
}

// ---------------- conv1 + max_k -> feats_bf[:, 0:64] ------------------------
__global__ void __launch_bounds__(64) k_conv1(const float* __restrict__ xt,
                                              const int* __restrict__ idx,
                                              const float* __restrict__ w,
                                              const float* __restrict__ bias,
                                              __hip_bfloat16* __restrict__ feats_bf) {
  int row = blockIdx.x;
  int t = threadIdx.x;
  int b = row >> 10;
  __shared__ float ws[64 * 18];
  __shared__ __align__(16) float diff_s[KNN][12];
  __shared__ float ctr_s[9];
  for (int i = t; i < 64 * 18; i += 64) ws[i] = w[i];
  if (t < 9) ctr_s[t] = xt[row * 9 + t];
  __syncthreads();
  if (t < KNN) {
    int j = idx[row * KNN + t];
    const float* xj = xt + ((b << 10) + j) * 9;
#pragma unroll
    for (int c = 0; c < 9; c++) diff_s[t][c] = xj[c] - ctr_s[c];
  }
  __syncthreads();
  float wd[9];
#pragma unroll
  for (int c = 0; c < 9; c++) wd[c] = ws[t * 18 + c];
  float cd = 0.f;
#pragma unroll
  for (int c = 0; c < 9; c++) cd = fmaf(ctr_s[c], ws[t * 18 + 9 + c], cd);
  float best = -3.0e38f;
  for (int k = 0; k < KNN; k++) {
    const float4* dr = (const float4*)diff_s[k];
    float4 d0 = dr[0], d1 = dr[1], d2v = dr[2];
    float dd = 0.f;
    dd = fmaf(d0.x, wd[0], dd); dd = fmaf(d0.y, wd[1], dd);
    dd = fmaf(d0.z, wd[2], dd); dd = fmaf(d0.w, wd[3], dd);
    dd = fmaf(d1.x, wd[4], dd); dd = fmaf(d1.y, wd[5], dd);
    dd = fmaf(d1.z, wd[6], dd); dd = fmaf(d1.w, wd[7], dd);
    dd = fmaf(d2v.x, wd[8], dd);
    best = fmaxf(best, dd);
  }
  float val = (best + cd + bias[t]) * BNS;
  feats_bf[row * FD + t] = __float2bfloat16(fmaxf(val, 0.f));
}

// ---------------- fused scorenet + g/H build: 4 rows per 256-thread block ---
__global__ void __launch_bounds__(256) k_g(const float* __restrict__ xt,
                                           const int* __restrict__ idx,
                                           const float* __restrict__ hw,
                                           const float* __restrict__ ow,
                                           const float* __restrict__ ob,
                                           const __hip_bfloat16* __restrict__ feats_bf,
                                           __hip_bfloat16* __restrict__ H, int l) {
  int row0 = blockIdx.x * 4;
  int t = threadIdx.x;
  int b = row0 >> 10;
  __shared__ float hws[HID * 28];
  __shared__ float ows[MM * HID];
  __shared__ float obs[MM];
  __shared__ __align__(16) float sc[4][KNN][8];
  __shared__ __align__(16) float ssum[4][8];
  __shared__ int js[4][KNN];
  __shared__ float ctr[4][9];
  for (int i = t; i < HID * 28; i += 256) hws[i] = hw[l * HID * 28 + i];
  if (t < MM * HID) ows[t] = ow[l * MM * HID + t];
  if (t < MM) obs[t] = ob[l * MM + t];
  if (t < 36) { int r = t / 9, c = t - r * 9; ctr[r][c] = xt[(row0 + r) * 9 + c]; }
  if (t < 4 * KNN) {
    int r = t / KNN, k = t - r * KNN;
    js[r][k] = (b << 10) + idx[(row0 + r) * KNN + k];
  }
  __syncthreads();
  if (t < 4 * KNN) {
    int r = t / KNN, k = t - r * KNN;
    const float* xj = xt + js[r][k] * 9;
    float xv[28];
    float d2 = 0.f;
#pragma unroll
    for (int c = 0; c < 9; c++) {
      float nb = xj[c], ct = ctr[r][c], df = nb - ct;
      xv[c] = df; xv[9 + c] = nb; xv[18 + c] = ct;
      d2 = fmaf(df, df, d2);
    }
    xv[27] = sqrtf(d2);
    float hid[HID];
#pragma unroll
    for (int h = 0; h < HID; h++) {
      float a = 0.f;
#pragma unroll
      for (int c = 0; c < 28; c++) a = fmaf(xv[c], hws[h * 28 + c], a);
      hid[h] = fmaxf(a * BNS, 0.f);
    }
    float lg[MM], mx = -3.0e38f;
#pragma unroll
    for (int m = 0; m < MM; m++) {
      float a = obs[m];
#pragma unroll
      for (int h = 0; h < HID; h++) a = fmaf(hid[h], ows[m * HID + h], a);
      lg[m] = a; mx = fmaxf(mx, a);
    }
    float s = 0.f;
#pragma unroll
    for (int m = 0; m < MM; m++) { lg[m] = __expf(lg[m] - mx); s += lg[m]; }
    float inv = 1.0f / s;
#pragma unroll
    for (int m = 0; m < MM; m++) sc[r][k][m] = lg[m] * inv;
  }
  __syncthreads();
  if (t < 32) {
    int r = t >> 3, m = t & 7;
    float a = 0.f;
#pragma unroll
    for (int k = 0; k < KNN; k++) a += sc[r][k][m];
    ssum[r][m] = a;
  }
  __syncthreads();
  // phase B: wave r, lane c: g[m] = sum_k sc[r][k][m] * f[j_k][c]
  int r = t >> 6, c = t & 63;
  int row = row0 + r;
  float g[MM] = {};
  for (int k = 0; k < KNN; k++) {
    float fv = __bfloat162float(feats_bf[js[r][k] * FD + l * 64 + c]);
    const float4* s4 = (const float4*)sc[r][k];
    float4 s0 = s4[0], s1 = s4[1];
    g[0] = fmaf(s0.x, fv, g[0]); g[1] = fmaf(s0.y, fv, g[1]);
    g[2] = fmaf(s0.z, fv, g[2]); g[3] = fmaf(s0.w, fv, g[3]);
    g[4] = fmaf(s1.x, fv, g[4]); g[5] = fmaf(s1.y, fv, g[5]);
    g[6] = fmaf(s1.z, fv, g[6]); g[7] = fmaf(s1.w, fv, g[7]);
  }
  float fn = __bfloat162float(feats_bf[row * FD + l * 64 + c]);
  __hip_bfloat16* Hrow = H + row * 1024;
#pragma unroll
  for (int m = 0; m < MM; m++) {
    Hrow[m * 64 + c] = __float2bfloat16(g[m] - ssum[r][m] * fn);   // hT -> kT
    Hrow[512 + m * 64 + c] = __float2bfloat16(g[m]);               // g  -> kB
  }
}

// ---------------- H @ K2 via MFMA: 1 wave/block, 16 rows x 64 cols ----------
__global__ void __launch_bounds__(64) k_hgemm(const __hip_bfloat16* __restrict__ H,
                                              const __hip_bfloat16* __restrict__ k2t_bf,
                                              __hip_bfloat16* __restrict__ feats_bf,
                                              int l) {
  int row0 = blockIdx.x * 16;
  int lane = threadIdx.x;
  int lr = lane & 15, lk8 = (lane >> 4) * 8;
  const short* Hs = (const short*)H;
  const short* Ks = (const short*)(k2t_bf + l * 64 * 1024);
  const short* arow = Hs + (row0 + lr) * 1024 + lk8;
  const short* b0r = Ks + lr * 1024 + lk8;
  f32x4 acc[4] = {{0.f, 0.f, 0.f, 0.f}, {0.f, 0.f, 0.f, 0.f},
                  {0.f, 0.f, 0.f, 0.f}, {0.f, 0.f, 0.f, 0.f}};
#pragma unroll 4
  for (int kk = 0; kk < 32; kk++) {
    int k0 = kk * 32;
    s16x8 a = *(const s16x8*)(arow + k0);
#pragma unroll
    for (int tn = 0; tn < 4; tn++) {
      s16x8 bb = *(const s16x8*)(b0r + tn * 16 * 1024 + k0);
      acc[tn] = __builtin_amdgcn_mfma_f32_16x16x32_bf16(a, bb, acc[tn], 0, 0, 0);
    }
  }
#pragma unroll
  for (int tn = 0; tn < 4; tn++) {
#pragma unroll
    for (int i = 0; i < 4; i++) {
      int row = row0 + (lane >> 4) * 4 + i;
      int o = tn * 16 + lr;
      float val = fmaxf(acc[tn][i] * BNS, 0.f);
      feats_bf[row * FD + (l + 1) * 64 + o] = __float2bfloat16(val);
    }
  }
}

// ---------------- final: feats_bf @ convt^T via MFMA + colmax + atomicMax ---
__global__ void __launch_bounds__(256) k_final(const __hip_bfloat16* __restrict__ feats_bf,
                                               const __hip_bfloat16* __restrict__ cvt_bf,
                                               float* __restrict__ out) {
  int m0 = (blockIdx.x >> 1) * 16;
  int nhalf = (blockIdx.x & 1) * 256;
  int w = threadIdx.x >> 6;
  int lane = threadIdx.x & 63;
  int lr = lane & 15, lk8 = (lane >> 4) * 8;
  int b = m0 >> 10;
  const short* Fs = (const short*)feats_bf;
  const short* Ws = (const short*)cvt_bf;
  const short* arow = Fs + (m0 + lr) * FD + lk8;
  int nbase = nhalf + w * 64;
  const short* brow = Ws + (nbase + lr) * FD + lk8;
  f32x4 acc[4] = {{0.f, 0.f, 0.f, 0.f}, {0.f, 0.f, 0.f, 0.f},
                  {0.f, 0.f, 0.f, 0.f}, {0.f, 0.f, 0.f, 0.f}};
#pragma unroll
  for (int kk = 0; kk < 10; kk++) {
    int k0 = kk * 32;
    s16x8 a = *(const s16x8*)(arow + k0);
#pragma unroll
    for (int tn = 0; tn < 4; tn++) {
      s16x8 bb = *(const s16x8*)(brow + tn * 16 * FD + k0);
      acc[tn] = __builtin_amdgcn_mfma_f32_16x16x32_bf16(a, bb, acc[tn], 0, 0, 0);
    }
  }
#pragma unroll
  for (int tn = 0; tn < 4; tn++) {
    float mx = fmaxf(fmaxf(acc[tn][0], acc[tn][1]), fmaxf(acc[tn][2], acc[tn][3]));
    mx = fmaxf(mx, __shfl_xor(mx, 16, 64));
    mx = fmaxf(mx, __shfl_xor(mx, 32, 64));
    if ((lane >> 4) == 0) {
      float val = fmaxf(mx * BNS, 0.f);
      int o = nbase + tn * 16 + lr;
      atomicMax((unsigned int*)out + b * OUTC + o, __float_as_uint(val));
    }
  }
}

extern "C" void kernel_launch(void* const* d_in, const int* in_sizes, int n_in,
                              void* d_out, int out_size, void* d_ws, size_t ws_size,
                              hipStream_t stream) {
  const float* x       = (const float*)d_in[0];
  const float* conv1_w = (const float*)d_in[3];
  const float* conv1_b = (const float*)d_in[4];
  const float* sn_hw   = (const float*)d_in[5];
  const float* sn_ow   = (const float*)d_in[6];
  const float* sn_ob   = (const float*)d_in[7];
  const float* mats    = (const float*)d_in[8];
  const float* convt_w = (const float*)d_in[9];
  float* out = (float*)d_out;

  float* w = (float*)d_ws;
  float* xt = w + OFF_XT;
  float* sq = w + OFF_SQ;
  int* idx = (int*)(w + OFF_IDX);
  __hip_bfloat16* cvt_bf = (__hip_bfloat16*)(w + OFF_CVT);
  __hip_bfloat16* k2t_bf = (__hip_bfloat16*)(w + OFF_K2T);
  __hip_bfloat16* feats_bf = (__hip_bfloat16*)(w + OFF_FB);
  __hip_bfloat16* H = (__hip_bfloat16*)(w + OFF_H);

  k_prep<<<1024, 256, 0, stream>>>(x, convt_w, mats, xt, sq, cvt_bf, k2t_bf, out);
  k_knn<<<1024, 256, 0, stream>>>(xt, sq, idx);
  k_conv1<<<4096, 64, 0, stream>>>(xt, idx, conv1_w, conv1_b, feats_bf);
  for (int l = 0; l < 4; l++) {
    k_g<<<1024, 256, 0, stream>>>(xt, idx, sn_hw, sn_ow, sn_ob, feats_bf, H, l);
    k_hgemm<<<256, 64, 0, stream>>>(H, k2t_bf, feats_bf, l);
  }
  k_final<<<512, 256, 0, stream>>>(feats_bf, cvt_bf, out);
}

// Round 6
// 215.994 us; speedup vs baseline: 1.9175x; 1.0871x over previous
//
#include <hip/hip_runtime.h>
#include <hip/hip_bf16.h>

// Problem constants
#define B 4
#define N 1024
#define KNN 30
#define MM 8
#define OO 64
#define OUTC 512
#define HID 16
#define FD 320
#define BNS 0.9999950000374997f   // 1/sqrt(1+1e-5)

typedef float f32x4 __attribute__((ext_vector_type(4)));
typedef short s16x8 __attribute__((ext_vector_type(8)));

// workspace float offsets
#define OFF_XT     0          // 36864 floats
#define OFF_SQ     36864      // 4096
#define OFF_IDX    40960      // 122880 ints
#define OFF_CVT    163840     // convt bf16: 512*320
#define OFF_K2T    245760     // 4*64*1024 bf16
#define OFF_FB     376832     // feats bf16: 4096*320
#define OFF_H      1032192    // H bf16: 4096*1024

// ---------------- prep: xt/sq, zero out, cvt bf16 ---------------------------
__global__ void __launch_bounds__(256) k_prep(const float* __restrict__ x,
                                              const float* __restrict__ convt_w,
                                              float* __restrict__ xt,
                                              float* __restrict__ sq,
                                              __hip_bfloat16* __restrict__ cvt_bf,
                                              float* __restrict__ out) {
  int id = blockIdx.x * 256 + threadIdx.x;   // grid 640*256
  if (id < B * N) {
    int b = id >> 10, n = id & 1023;
    float s = 0.f;
#pragma unroll
    for (int c = 0; c < 9; c++) {
      float v = x[(b * 9 + c) * N + n];
      xt[id * 9 + c] = v;
      s = fmaf(v, v, s);
    }
    sq[id] = s;
  }
  if (id < B * OUTC) out[id] = 0.f;
  if (id < 512 * 320) cvt_bf[id] = __float2bfloat16(convt_w[id]);
}

// ---------------- k2t transpose via LDS tile (coalesced both sides) ---------
__global__ void __launch_bounds__(256) k_tpose(const float* __restrict__ mats,
                                               __hip_bfloat16* __restrict__ k2t_bf) {
  int blk = blockIdx.x;              // l*16 + part*8 + m  (64 blocks)
  int l = blk >> 4, part = (blk >> 3) & 1, m = blk & 7;
  __shared__ float tile[64][65];
  int tr = threadIdx.x >> 6;         // 0..3
  int tc = threadIdx.x & 63;
  const float* src = mats + l * 65536 + (part * 64) * 512 + m * 64;
#pragma unroll
  for (int it = 0; it < 16; it++) {
    int c = it * 4 + tr;
    tile[c][tc] = src[c * 512 + tc];
  }
  __syncthreads();
  __hip_bfloat16* dst = k2t_bf + l * 65536 + part * 512 + m * 64;
#pragma unroll
  for (int it = 0; it < 16; it++) {
    int o = it * 4 + tr;
    dst[o * 1024 + tc] = __float2bfloat16(tile[tc][o]);
  }
}

// ---------------- knn: exact top-30 via 4-pass radix select -----------------
// key = sign-flipped float bits (strictly monotone); downstream is order-
// invariant over k, and ==T ties are taken in ascending idx (JAX-stable).
__global__ void __launch_bounds__(256) k_knn(const float* __restrict__ xt,
                                             const float* __restrict__ sq,
                                             int* __restrict__ idx) {
  int r = threadIdx.x >> 6;          // row-in-block 0..3
  int lane = threadIdx.x & 63;
  int row = blockIdx.x * 4 + r;
  int b = row >> 10;
  __shared__ unsigned int hist[4][256];
  __shared__ unsigned int cntr[4];
  __shared__ unsigned int bp[4];
  __shared__ int bn[4];
  const float* xb = xt + (b << 10) * 9;
  const float* sb = sq + (b << 10);
  float cx[9];
#pragma unroll
  for (int c = 0; c < 9; c++) cx[c] = xt[row * 9 + c];
  float sqn = sq[row];
  unsigned int key[16];
#pragma unroll
  for (int s = 0; s < 16; s++) {
    int j = s * 64 + lane;
    const float* xj = xb + j * 9;
    float dot = 0.f;
#pragma unroll
    for (int c = 0; c < 9; c++) dot = fmaf(cx[c], xj[c], dot);
    float v = 2.0f * dot - sqn - sb[j];   // exactly 0 for j==n (same fmaf order)
    unsigned int u = __float_as_uint(v);
    key[s] = u ^ ((unsigned int)(((int)u) >> 31) | 0x80000000u);  // asc-sortable
  }
  if (lane == 0) cntr[r] = 0;
  unsigned int prefix = 0;
  int need = KNN;
  for (int p = 0; p < 4; p++) {
    int shift = 24 - 8 * p;
    for (int i = lane; i < 256; i += 64) hist[r][i] = 0;
    __syncthreads();
    unsigned int himask = (p == 0) ? 0u : (0xFFFFFFFFu << (shift + 8));
#pragma unroll
    for (int s = 0; s < 16; s++) {
      if ((key[s] & himask) == prefix)
        atomicAdd(&hist[r][(key[s] >> shift) & 255], 1u);
    }
    __syncthreads();
    // descending-rank scan: lane l owns digits 4l..4l+3
    int c0 = hist[r][4 * lane + 0], c1 = hist[r][4 * lane + 1];
    int c2 = hist[r][4 * lane + 2], c3 = hist[r][4 * lane + 3];
    int lsum = c0 + c1 + c2 + c3;
    int sfx = lsum;   // inclusive suffix sum over lanes
#pragma unroll
    for (int ofs = 1; ofs < 64; ofs <<= 1) {
      int t = __shfl_down(sfx, ofs, 64);
      if (lane + ofs < 64) sfx += t;
    }
    int A3 = sfx - lsum;        // count of elements with digit > 4l+3
    int A2 = A3 + c3, A1 = A2 + c2, A0 = A1 + c1;
    // the intervals (A(d), A(d)+cnt(d)] partition; exactly one holds `need`
    if (A0 < need && need <= A0 + c0) { bp[r] = prefix | ((unsigned)(4 * lane + 0) << shift); bn[r] = need - A0; }
    if (A1 < need && need <= A1 + c1) { bp[r] = prefix | ((unsigned)(4 * lane + 1) << shift); bn[r] = need - A1; }
    if (A2 < need && need <= A2 + c2) { bp[r] = prefix | ((unsigned)(4 * lane + 2) << shift); bn[r] = need - A2; }
    if (A3 < need && need <= A3 + c3) { bp[r] = prefix | ((unsigned)(4 * lane + 3) << shift); bn[r] = need - A3; }
    __syncthreads();
    prefix = bp[r];
    need = bn[r];
  }
  unsigned int T = prefix;            // exact 30th-largest key
  int above_total = KNN - need;       // #(key > T)
  int* orow = idx + row * KNN;
#pragma unroll
  for (int s = 0; s < 16; s++) {
    if (key[s] > T) {
      unsigned int pslot = atomicAdd(&cntr[r], 1u);
      orow[pslot] = s * 64 + lane;
    }
  }
  // ==T in ascending idx order (s-major == idx-major)
  int base = 0;
  for (int s = 0; s < 16; s++) {
    unsigned long long m = __ballot(key[s] == T);
    if (key[s] == T) {
      int rk = base + __popcll(m & ((1ull << lane) - 1ull));
      if (rk < need) orow[above_total + rk] = s * 64 + lane;
    }
    base += __popcll(m);
    if (base >= need) break;          // uniform (ballot-derived)
  }
}

// ---------------- conv1 + max_k -> feats_bf[:, 0:64] ------------------------
__global__ void __launch_bounds__(64) k_conv1(const float* __restrict__ xt,
                                              const int* __restrict__ idx,
                                              const float* __restrict__ w,
                                              const float* __restrict__ bias,
                                              __hip_bfloat16* __restrict__ feats_bf) {
  int row = blockIdx.x;
  int t = threadIdx.x;
  int b = row >> 10;
  __shared__ float ws[64 * 18];
  __shared__ __align__(16) float diff_s[KNN][12];
  __shared__ float ctr_s[9];
  for (int i = t; i < 64 * 18; i += 64) ws[i] = w[i];
  if (t < 9) ctr_s[t] = xt[row * 9 + t];
  __syncthreads();
  if (t < KNN) {
    int j = idx[row * KNN + t];
    const float* xj = xt + ((b << 10) + j) * 9;
#pragma unroll
    for (int c = 0; c < 9; c++) diff_s[t][c] = xj[c] - ctr_s[c];
  }
  __syncthreads();
  float wd[9];
#pragma unroll
  for (int c = 0; c < 9; c++) wd[c] = ws[t * 18 + c];
  float cd = 0.f;
#pragma unroll
  for (int c = 0; c < 9; c++) cd = fmaf(ctr_s[c], ws[t * 18 + 9 + c], cd);
  float best = -3.0e38f;
  for (int k = 0; k < KNN; k++) {
    const float4* dr = (const float4*)diff_s[k];
    float4 d0 = dr[0], d1 = dr[1], d2v = dr[2];
    float dd = 0.f;
    dd = fmaf(d0.x, wd[0], dd); dd = fmaf(d0.y, wd[1], dd);
    dd = fmaf(d0.z, wd[2], dd); dd = fmaf(d0.w, wd[3], dd);
    dd = fmaf(d1.x, wd[4], dd); dd = fmaf(d1.y, wd[5], dd);
    dd = fmaf(d1.z, wd[6], dd); dd = fmaf(d1.w, wd[7], dd);
    dd = fmaf(d2v.x, wd[8], dd);
    best = fmaxf(best, dd);
  }
  float val = (best + cd + bias[t]) * BNS;
  feats_bf[row * FD + t] = __float2bfloat16(fmaxf(val, 0.f));
}

// ---------------- fused scorenet + g/H build: 4 rows per 256-thread block ---
__global__ void __launch_bounds__(256) k_g(const float* __restrict__ xt,
                                           const int* __restrict__ idx,
                                           const float* __restrict__ hw,
                                           const float* __restrict__ ow,
                                           const float* __restrict__ ob,
                                           const __hip_bfloat16* __restrict__ feats_bf,
                                           __hip_bfloat16* __restrict__ H, int l) {
  int row0 = blockIdx.x * 4;
  int t = threadIdx.x;
  int b = row0 >> 10;
  __shared__ float hws[HID * 28];
  __shared__ float ows[MM * HID];
  __shared__ float obs[MM];
  __shared__ __align__(16) float sc[4][KNN][8];
  __shared__ __align__(16) float ssum[4][8];
  __shared__ int js[4][KNN];
  __shared__ float ctr[4][9];
  for (int i = t; i < HID * 28; i += 256) hws[i] = hw[l * HID * 28 + i];
  if (t < MM * HID) ows[t] = ow[l * MM * HID + t];
  if (t < MM) obs[t] = ob[l * MM + t];
  if (t < 36) { int r = t / 9, c = t - r * 9; ctr[r][c] = xt[(row0 + r) * 9 + c]; }
  if (t < 4 * KNN) {
    int r = t / KNN, k = t - r * KNN;
    js[r][k] = (b << 10) + idx[(row0 + r) * KNN + k];
  }
  __syncthreads();
  if (t < 4 * KNN) {
    int r = t / KNN, k = t - r * KNN;
    const float* xj = xt + js[r][k] * 9;
    float xv[28];
    float d2 = 0.f;
#pragma unroll
    for (int c = 0; c < 9; c++) {
      float nb = xj[c], ct = ctr[r][c], df = nb - ct;
      xv[c] = df; xv[9 + c] = nb; xv[18 + c] = ct;
      d2 = fmaf(df, df, d2);
    }
    xv[27] = sqrtf(d2);
    float hid[HID];
#pragma unroll
    for (int h = 0; h < HID; h++) {
      float a = 0.f;
#pragma unroll
      for (int c = 0; c < 28; c++) a = fmaf(xv[c], hws[h * 28 + c], a);
      hid[h] = fmaxf(a * BNS, 0.f);
    }
    float lg[MM], mx = -3.0e38f;
#pragma unroll
    for (int m = 0; m < MM; m++) {
      float a = obs[m];
#pragma unroll
      for (int h = 0; h < HID; h++) a = fmaf(hid[h], ows[m * HID + h], a);
      lg[m] = a; mx = fmaxf(mx, a);
    }
    float s = 0.f;
#pragma unroll
    for (int m = 0; m < MM; m++) { lg[m] = __expf(lg[m] - mx); s += lg[m]; }
    float inv = 1.0f / s;
#pragma unroll
    for (int m = 0; m < MM; m++) sc[r][k][m] = lg[m] * inv;
  }
  __syncthreads();
  if (t < 32) {
    int r = t >> 3, m = t & 7;
    float a = 0.f;
#pragma unroll
    for (int k = 0; k < KNN; k++) a += sc[r][k][m];
    ssum[r][m] = a;
  }
  __syncthreads();
  int r = t >> 6, c = t & 63;
  int row = row0 + r;
  float g[MM] = {};
  for (int k = 0; k < KNN; k++) {
    float fv = __bfloat162float(feats_bf[js[r][k] * FD + l * 64 + c]);
    const float4* s4 = (const float4*)sc[r][k];
    float4 s0 = s4[0], s1 = s4[1];
    g[0] = fmaf(s0.x, fv, g[0]); g[1] = fmaf(s0.y, fv, g[1]);
    g[2] = fmaf(s0.z, fv, g[2]); g[3] = fmaf(s0.w, fv, g[3]);
    g[4] = fmaf(s1.x, fv, g[4]); g[5] = fmaf(s1.y, fv, g[5]);
    g[6] = fmaf(s1.z, fv, g[6]); g[7] = fmaf(s1.w, fv, g[7]);
  }
  float fn = __bfloat162float(feats_bf[row * FD + l * 64 + c]);
  __hip_bfloat16* Hrow = H + row * 1024;
#pragma unroll
  for (int m = 0; m < MM; m++) {
    Hrow[m * 64 + c] = __float2bfloat16(g[m] - ssum[r][m] * fn);   // pairs kern[:64]
    Hrow[512 + m * 64 + c] = __float2bfloat16(g[m]);               // pairs kern[64:]
  }
}

// ---------------- H @ K2 via MFMA: 1 wave = 16 rows x 16 cols ---------------
__global__ void __launch_bounds__(64) k_hgemm(const __hip_bfloat16* __restrict__ H,
                                              const __hip_bfloat16* __restrict__ k2t_bf,
                                              __hip_bfloat16* __restrict__ feats_bf,
                                              int l) {
  int rb = blockIdx.x >> 2, cb = blockIdx.x & 3;
  int row0 = rb * 16, c0 = cb * 16;
  int lane = threadIdx.x;
  int lr = lane & 15, lk8 = (lane >> 4) * 8;
  const short* Hs = (const short*)H;
  const short* Ks = (const short*)(k2t_bf + l * 65536);
  const short* arow = Hs + (row0 + lr) * 1024 + lk8;
  const short* brow = Ks + (c0 + lr) * 1024 + lk8;
  f32x4 acc = {0.f, 0.f, 0.f, 0.f};
#pragma unroll 8
  for (int kk = 0; kk < 32; kk++) {
    s16x8 a = *(const s16x8*)(arow + kk * 32);
    s16x8 bb = *(const s16x8*)(brow + kk * 32);
    acc = __builtin_amdgcn_mfma_f32_16x16x32_bf16(a, bb, acc, 0, 0, 0);
  }
#pragma unroll
  for (int i = 0; i < 4; i++) {
    int row = row0 + (lane >> 4) * 4 + i;
    feats_bf[row * FD + (l + 1) * 64 + c0 + lr] =
        __float2bfloat16(fmaxf(acc[i] * BNS, 0.f));
  }
}

// ---------------- final: feats_bf @ convt^T via MFMA + colmax + atomicMax ---
__global__ void __launch_bounds__(256) k_final(const __hip_bfloat16* __restrict__ feats_bf,
                                               const __hip_bfloat16* __restrict__ cvt_bf,
                                               float* __restrict__ out) {
  int m0 = (blockIdx.x >> 1) * 16;
  int nhalf = (blockIdx.x & 1) * 256;
  int w = threadIdx.x >> 6;
  int lane = threadIdx.x & 63;
  int lr = lane & 15, lk8 = (lane >> 4) * 8;
  int b = m0 >> 10;
  const short* Fs = (const short*)feats_bf;
  const short* Ws = (const short*)cvt_bf;
  const short* arow = Fs + (m0 + lr) * FD + lk8;
  int nbase = nhalf + w * 64;
  const short* brow = Ws + (nbase + lr) * FD + lk8;
  f32x4 acc[4] = {{0.f, 0.f, 0.f, 0.f}, {0.f, 0.f, 0.f, 0.f},
                  {0.f, 0.f, 0.f, 0.f}, {0.f, 0.f, 0.f, 0.f}};
#pragma unroll
  for (int kk = 0; kk < 10; kk++) {
    int k0 = kk * 32;
    s16x8 a = *(const s16x8*)(arow + k0);
#pragma unroll
    for (int tn = 0; tn < 4; tn++) {
      s16x8 bb = *(const s16x8*)(brow + tn * 16 * FD + k0);
      acc[tn] = __builtin_amdgcn_mfma_f32_16x16x32_bf16(a, bb, acc[tn], 0, 0, 0);
    }
  }
#pragma unroll
  for (int tn = 0; tn < 4; tn++) {
    float mx = fmaxf(fmaxf(acc[tn][0], acc[tn][1]), fmaxf(acc[tn][2], acc[tn][3]));
    mx = fmaxf(mx, __shfl_xor(mx, 16, 64));
    mx = fmaxf(mx, __shfl_xor(mx, 32, 64));
    if ((lane >> 4) == 0) {
      float val = fmaxf(mx * BNS, 0.f);
      int o = nbase + tn * 16 + lr;
      atomicMax((unsigned int*)out + b * OUTC + o, __float_as_uint(val));
    }
  }
}

extern "C" void kernel_launch(void* const* d_in, const int* in_sizes, int n_in,
                              void* d_out, int out_size, void* d_ws, size_t ws_size,
                              hipStream_t stream) {
  const float* x       = (const float*)d_in[0];
  const float* conv1_w = (const float*)d_in[3];
  const float* conv1_b = (const float*)d_in[4];
  const float* sn_hw   = (const float*)d_in[5];
  const float* sn_ow   = (const float*)d_in[6];
  const float* sn_ob   = (const float*)d_in[7];
  const float* mats    = (const float*)d_in[8];
  const float* convt_w = (const float*)d_in[9];
  float* out = (float*)d_out;

  float* w = (float*)d_ws;
  float* xt = w + OFF_XT;
  float* sq = w + OFF_SQ;
  int* idx = (int*)(w + OFF_IDX);
  __hip_bfloat16* cvt_bf = (__hip_bfloat16*)(w + OFF_CVT);
  __hip_bfloat16* k2t_bf = (__hip_bfloat16*)(w + OFF_K2T);
  __hip_bfloat16* feats_bf = (__hip_bfloat16*)(w + OFF_FB);
  __hip_bfloat16* H = (__hip_bfloat16*)(w + OFF_H);

  k_prep<<<640, 256, 0, stream>>>(x, convt_w, xt, sq, cvt_bf, out);
  k_tpose<<<64, 256, 0, stream>>>(mats, k2t_bf);
  k_knn<<<1024, 256, 0, stream>>>(xt, sq, idx);
  k_conv1<<<4096, 64, 0, stream>>>(xt, idx, conv1_w, conv1_b, feats_bf);
  for (int l = 0; l < 4; l++) {
    k_g<<<1024, 256, 0, stream>>>(xt, idx, sn_hw, sn_ow, sn_ob, feats_bf, H, l);
    k_hgemm<<<1024, 64, 0, stream>>>(H, k2t_bf, feats_bf, l);
  }
  k_final<<<512, 256, 0, stream>>>(feats_bf, cvt_bf, out);
}

// Round 7
// 208.040 us; speedup vs baseline: 1.9908x; 1.0382x over previous
//
#include <hip/hip_runtime.h>
#include <hip/hip_bf16.h>

// Problem constants
#define B 4
#define N 1024
#define KNN 30
#define MM 8
#define OO 64
#define OUTC 512
#define HID 16
#define FD 320
#define BNS 0.9999950000374997f   // 1/sqrt(1+1e-5)

typedef float f32x4 __attribute__((ext_vector_type(4)));
typedef short s16x8 __attribute__((ext_vector_type(8)));

// workspace float offsets
#define OFF_XT     0          // 36864 floats
#define OFF_SQ     36864      // 4096
#define OFF_IDX    40960      // 122880 ints
#define OFF_CVT    163840     // convt bf16: 512*320
#define OFF_K2T    245760     // 4*64*1024 bf16
#define OFF_FB     376832     // feats bf16: 4096*320

// ---------------- prep (+ k2t transpose): one kernel, branch on blockIdx ----
__global__ void __launch_bounds__(256) k_prep(const float* __restrict__ x,
                                              const float* __restrict__ convt_w,
                                              const float* __restrict__ mats,
                                              float* __restrict__ xt,
                                              float* __restrict__ sq,
                                              __hip_bfloat16* __restrict__ cvt_bf,
                                              __hip_bfloat16* __restrict__ k2t_bf,
                                              float* __restrict__ out) {
  __shared__ float tile[64][65];
  if (blockIdx.x < 640) {
    int id = blockIdx.x * 256 + threadIdx.x;
    if (id < B * N) {
      int b = id >> 10, n = id & 1023;
      float s = 0.f;
#pragma unroll
      for (int c = 0; c < 9; c++) {
        float v = x[(b * 9 + c) * N + n];
        xt[id * 9 + c] = v;
        s = fmaf(v, v, s);
      }
      sq[id] = s;
    }
    if (id < B * OUTC) out[id] = 0.f;
    if (id < 512 * 320) cvt_bf[id] = __float2bfloat16(convt_w[id]);
  } else {
    int blk = blockIdx.x - 640;        // l*16 + part*8 + m  (64 blocks)
    int l = blk >> 4, part = (blk >> 3) & 1, m = blk & 7;
    int tr = threadIdx.x >> 6;         // 0..3
    int tc = threadIdx.x & 63;
    const float* src = mats + l * 65536 + (part * 64) * 512 + m * 64;
#pragma unroll
    for (int it = 0; it < 16; it++) {
      int c = it * 4 + tr;
      tile[c][tc] = src[c * 512 + tc];
    }
    __syncthreads();
    __hip_bfloat16* dst = k2t_bf + l * 65536 + part * 512 + m * 64;
#pragma unroll
    for (int it = 0; it < 16; it++) {
      int o = it * 4 + tr;
      dst[o * 1024 + tc] = __float2bfloat16(tile[tc][o]);
    }
  }
}

// ---------------- knn: exact top-30 via 4-pass radix select -----------------
__global__ void __launch_bounds__(256) k_knn(const float* __restrict__ xt,
                                             const float* __restrict__ sq,
                                             int* __restrict__ idx) {
  int r = threadIdx.x >> 6;
  int lane = threadIdx.x & 63;
  int row = blockIdx.x * 4 + r;
  int b = row >> 10;
  __shared__ unsigned int hist[4][256];
  __shared__ unsigned int cntr[4];
  __shared__ unsigned int bp[4];
  __shared__ int bn[4];
  const float* xb = xt + (b << 10) * 9;
  const float* sb = sq + (b << 10);
  float cx[9];
#pragma unroll
  for (int c = 0; c < 9; c++) cx[c] = xt[row * 9 + c];
  float sqn = sq[row];
  unsigned int key[16];
#pragma unroll
  for (int s = 0; s < 16; s++) {
    int j = s * 64 + lane;
    const float* xj = xb + j * 9;
    float dot = 0.f;
#pragma unroll
    for (int c = 0; c < 9; c++) dot = fmaf(cx[c], xj[c], dot);
    float v = 2.0f * dot - sqn - sb[j];   // exactly 0 for j==n (same fmaf order)
    unsigned int u = __float_as_uint(v);
    key[s] = u ^ ((unsigned int)(((int)u) >> 31) | 0x80000000u);  // asc-sortable
  }
  if (lane == 0) cntr[r] = 0;
  unsigned int prefix = 0;
  int need = KNN;
  for (int p = 0; p < 4; p++) {
    int shift = 24 - 8 * p;
    for (int i = lane; i < 256; i += 64) hist[r][i] = 0;
    __syncthreads();
    unsigned int himask = (p == 0) ? 0u : (0xFFFFFFFFu << (shift + 8));
#pragma unroll
    for (int s = 0; s < 16; s++) {
      if ((key[s] & himask) == prefix)
        atomicAdd(&hist[r][(key[s] >> shift) & 255], 1u);
    }
    __syncthreads();
    int c0 = hist[r][4 * lane + 0], c1 = hist[r][4 * lane + 1];
    int c2 = hist[r][4 * lane + 2], c3 = hist[r][4 * lane + 3];
    int lsum = c0 + c1 + c2 + c3;
    int sfx = lsum;
#pragma unroll
    for (int ofs = 1; ofs < 64; ofs <<= 1) {
      int t = __shfl_down(sfx, ofs, 64);
      if (lane + ofs < 64) sfx += t;
    }
    int A3 = sfx - lsum;
    int A2 = A3 + c3, A1 = A2 + c2, A0 = A1 + c1;
    if (A0 < need && need <= A0 + c0) { bp[r] = prefix | ((unsigned)(4 * lane + 0) << shift); bn[r] = need - A0; }
    if (A1 < need && need <= A1 + c1) { bp[r] = prefix | ((unsigned)(4 * lane + 1) << shift); bn[r] = need - A1; }
    if (A2 < need && need <= A2 + c2) { bp[r] = prefix | ((unsigned)(4 * lane + 2) << shift); bn[r] = need - A2; }
    if (A3 < need && need <= A3 + c3) { bp[r] = prefix | ((unsigned)(4 * lane + 3) << shift); bn[r] = need - A3; }
    __syncthreads();
    prefix = bp[r];
    need = bn[r];
  }
  unsigned int T = prefix;
  int above_total = KNN - need;
  int* orow = idx + row * KNN;
#pragma unroll
  for (int s = 0; s < 16; s++) {
    if (key[s] > T) {
      unsigned int pslot = atomicAdd(&cntr[r], 1u);
      orow[pslot] = s * 64 + lane;
    }
  }
  int base = 0;
  for (int s = 0; s < 16; s++) {
    unsigned long long m = __ballot(key[s] == T);
    if (key[s] == T) {
      int rk = base + __popcll(m & ((1ull << lane) - 1ull));
      if (rk < need) orow[above_total + rk] = s * 64 + lane;
    }
    base += __popcll(m);
    if (base >= need) break;
  }
}

// ---------------- conv1 + max_k: 4 rows per 256-thread block ----------------
__global__ void __launch_bounds__(256) k_conv1(const float* __restrict__ xt,
                                               const int* __restrict__ idx,
                                               const float* __restrict__ w,
                                               const float* __restrict__ bias,
                                               __hip_bfloat16* __restrict__ feats_bf) {
  int row0 = blockIdx.x * 4;
  int t = threadIdx.x;
  int b = row0 >> 10;
  __shared__ float ws[64 * 18];
  __shared__ __align__(16) float diff_s[4][KNN][12];
  __shared__ float ctr_s[4][9];
  for (int i = t; i < 64 * 18; i += 256) ws[i] = w[i];
  if (t < 36) { int r = t / 9, c = t - r * 9; ctr_s[r][c] = xt[(row0 + r) * 9 + c]; }
  __syncthreads();
  if (t < 120) {
    int r = t / KNN, k = t - r * KNN;
    int j = idx[(row0 + r) * KNN + k];
    const float* xj = xt + ((b << 10) + j) * 9;
#pragma unroll
    for (int c = 0; c < 9; c++) diff_s[r][k][c] = xj[c] - ctr_s[r][c];
  }
  __syncthreads();
  int wv = t >> 6, lane = t & 63;
  int row = row0 + wv;
  float wd[9];
#pragma unroll
  for (int c = 0; c < 9; c++) wd[c] = ws[lane * 18 + c];
  float cd = 0.f;
#pragma unroll
  for (int c = 0; c < 9; c++) cd = fmaf(ctr_s[wv][c], ws[lane * 18 + 9 + c], cd);
  float best = -3.0e38f;
  for (int k = 0; k < KNN; k++) {
    const float4* dr = (const float4*)diff_s[wv][k];
    float4 d0 = dr[0], d1 = dr[1], d2v = dr[2];
    float dd = 0.f;
    dd = fmaf(d0.x, wd[0], dd); dd = fmaf(d0.y, wd[1], dd);
    dd = fmaf(d0.z, wd[2], dd); dd = fmaf(d0.w, wd[3], dd);
    dd = fmaf(d1.x, wd[4], dd); dd = fmaf(d1.y, wd[5], dd);
    dd = fmaf(d1.z, wd[6], dd); dd = fmaf(d1.w, wd[7], dd);
    dd = fmaf(d2v.x, wd[8], dd);
    best = fmaxf(best, dd);
  }
  float val = (best + cd + bias[lane]) * BNS;
  feats_bf[row * FD + lane] = __float2bfloat16(fmaxf(val, 0.f));
}

// ---------------- fused layer: scorenet + g + (H @ K2) MFMA -----------------
// block = 16 rows (256 threads, 4 waves), H kept in LDS (row pad 16 -> even
// 8-bank rotation per row = conflict-floor b128 reads)
__global__ void __launch_bounds__(256) k_layer(const float* __restrict__ xt,
                                               const int* __restrict__ idx,
                                               const float* __restrict__ hw,
                                               const float* __restrict__ ow,
                                               const float* __restrict__ ob,
                                               const __hip_bfloat16* __restrict__ k2t_bf,
                                               __hip_bfloat16* __restrict__ feats_bf,
                                               int l) {
  int row0 = blockIdx.x * 16;
  int t = threadIdx.x;
  int b = row0 >> 10;
  __shared__ float hws[HID * 28];
  __shared__ float ows[MM * HID];
  __shared__ float obs[MM];
  __shared__ int js[16][KNN];
  __shared__ float ctr[16][9];
  __shared__ __align__(16) float sc[16][KNN][8];
  __shared__ float ssum[16][8];
  __shared__ __align__(16) __hip_bfloat16 Hs[16][1040];   // 1024 + 16 pad
  for (int i = t; i < HID * 28; i += 256) hws[i] = hw[l * HID * 28 + i];
  if (t < MM * HID) ows[t] = ow[l * MM * HID + t];
  if (t < MM) obs[t] = ob[l * MM + t];
  if (t < 144) { int r = t / 9, c = t - r * 9; ctr[r][c] = xt[(row0 + r) * 9 + c]; }
  for (int i = t; i < 16 * KNN; i += 256) {
    int r = i / KNN, k = i - r * KNN;
    js[r][k] = (b << 10) + idx[(row0 + r) * KNN + k];
  }
  __syncthreads();
  // scorenet: 480 items over 256 threads
  for (int i = t; i < 16 * KNN; i += 256) {
    int r = i / KNN, k = i - r * KNN;
    const float* xj = xt + js[r][k] * 9;
    float xv[28];
    float d2 = 0.f;
#pragma unroll
    for (int c = 0; c < 9; c++) {
      float nb = xj[c], ct = ctr[r][c], df = nb - ct;
      xv[c] = df; xv[9 + c] = nb; xv[18 + c] = ct;
      d2 = fmaf(df, df, d2);
    }
    xv[27] = sqrtf(d2);
    float hid[HID];
#pragma unroll
    for (int h = 0; h < HID; h++) {
      float a = 0.f;
#pragma unroll
      for (int c = 0; c < 28; c++) a = fmaf(xv[c], hws[h * 28 + c], a);
      hid[h] = fmaxf(a * BNS, 0.f);
    }
    float lg[MM], mx = -3.0e38f;
#pragma unroll
    for (int m = 0; m < MM; m++) {
      float a = obs[m];
#pragma unroll
      for (int h = 0; h < HID; h++) a = fmaf(hid[h], ows[m * HID + h], a);
      lg[m] = a; mx = fmaxf(mx, a);
    }
    float s = 0.f;
#pragma unroll
    for (int m = 0; m < MM; m++) { lg[m] = __expf(lg[m] - mx); s += lg[m]; }
    float inv = 1.0f / s;
#pragma unroll
    for (int m = 0; m < MM; m++) sc[r][k][m] = lg[m] * inv;
  }
  __syncthreads();
  if (t < 128) {
    int r = t >> 3, m = t & 7;
    float a = 0.f;
#pragma unroll
    for (int k = 0; k < KNN; k++) a += sc[r][k][m];
    ssum[r][m] = a;
  }
  __syncthreads();
  // g phase: wave wv handles rows 4wv..4wv+3, lane = channel c
  int wv = t >> 6, lane = t & 63;
#pragma unroll
  for (int rr = 0; rr < 4; rr++) {
    int r = wv * 4 + rr;
    int row = row0 + r;
    float g[MM] = {};
#pragma unroll
    for (int k = 0; k < KNN; k++) {
      float fv = __bfloat162float(feats_bf[js[r][k] * FD + l * 64 + lane]);
      const float4* s4 = (const float4*)sc[r][k];
      float4 s0 = s4[0], s1 = s4[1];
      g[0] = fmaf(s0.x, fv, g[0]); g[1] = fmaf(s0.y, fv, g[1]);
      g[2] = fmaf(s0.z, fv, g[2]); g[3] = fmaf(s0.w, fv, g[3]);
      g[4] = fmaf(s1.x, fv, g[4]); g[5] = fmaf(s1.y, fv, g[5]);
      g[6] = fmaf(s1.z, fv, g[6]); g[7] = fmaf(s1.w, fv, g[7]);
    }
    float fn = __bfloat162float(feats_bf[row * FD + l * 64 + lane]);
#pragma unroll
    for (int m = 0; m < MM; m++) {
      Hs[r][m * 64 + lane] = __float2bfloat16(g[m] - ssum[r][m] * fn);
      Hs[r][512 + m * 64 + lane] = __float2bfloat16(g[m]);
    }
  }
  __syncthreads();
  // GEMM: wave wv -> 16 rows x cols [wv*16, wv*16+16), K = 1024
  int lr = lane & 15, lk8 = (lane >> 4) * 8;
  const short* Ks2 = (const short*)(k2t_bf + l * 65536);
  const short* brow = Ks2 + (wv * 16 + lr) * 1024 + lk8;
  const short* arow = (const short*)&Hs[lr][lk8];
  f32x4 acc = {0.f, 0.f, 0.f, 0.f};
#pragma unroll 8
  for (int kk = 0; kk < 32; kk++) {
    s16x8 a = *(const s16x8*)(arow + kk * 32);
    s16x8 bb = *(const s16x8*)(brow + kk * 32);
    acc = __builtin_amdgcn_mfma_f32_16x16x32_bf16(a, bb, acc, 0, 0, 0);
  }
#pragma unroll
  for (int i = 0; i < 4; i++) {
    int row = row0 + (lane >> 4) * 4 + i;
    feats_bf[row * FD + (l + 1) * 64 + wv * 16 + lr] =
        __float2bfloat16(fmaxf(acc[i] * BNS, 0.f));
  }
}

// ---------------- final: feats_bf @ convt^T via MFMA + colmax + atomicMax ---
__global__ void __launch_bounds__(256) k_final(const __hip_bfloat16* __restrict__ feats_bf,
                                               const __hip_bfloat16* __restrict__ cvt_bf,
                                               float* __restrict__ out) {
  int m0 = (blockIdx.x >> 1) * 16;
  int nhalf = (blockIdx.x & 1) * 256;
  int w = threadIdx.x >> 6;
  int lane = threadIdx.x & 63;
  int lr = lane & 15, lk8 = (lane >> 4) * 8;
  int b = m0 >> 10;
  const short* Fs = (const short*)feats_bf;
  const short* Ws = (const short*)cvt_bf;
  const short* arow = Fs + (m0 + lr) * FD + lk8;
  int nbase = nhalf + w * 64;
  const short* brow = Ws + (nbase + lr) * FD + lk8;
  f32x4 acc[4] = {{0.f, 0.f, 0.f, 0.f}, {0.f, 0.f, 0.f, 0.f},
                  {0.f, 0.f, 0.f, 0.f}, {0.f, 0.f, 0.f, 0.f}};
#pragma unroll
  for (int kk = 0; kk < 10; kk++) {
    int k0 = kk * 32;
    s16x8 a = *(const s16x8*)(arow + k0);
#pragma unroll
    for (int tn = 0; tn < 4; tn++) {
      s16x8 bb = *(const s16x8*)(brow + tn * 16 * FD + k0);
      acc[tn] = __builtin_amdgcn_mfma_f32_16x16x32_bf16(a, bb, acc[tn], 0, 0, 0);
    }
  }
#pragma unroll
  for (int tn = 0; tn < 4; tn++) {
    float mx = fmaxf(fmaxf(acc[tn][0], acc[tn][1]), fmaxf(acc[tn][2], acc[tn][3]));
    mx = fmaxf(mx, __shfl_xor(mx, 16, 64));
    mx = fmaxf(mx, __shfl_xor(mx, 32, 64));
    if ((lane >> 4) == 0) {
      float val = fmaxf(mx * BNS, 0.f);
      int o = nbase + tn * 16 + lr;
      atomicMax((unsigned int*)out + b * OUTC + o, __float_as_uint(val));
    }
  }
}

extern "C" void kernel_launch(void* const* d_in, const int* in_sizes, int n_in,
                              void* d_out, int out_size, void* d_ws, size_t ws_size,
                              hipStream_t stream) {
  const float* x       = (const float*)d_in[0];
  const float* conv1_w = (const float*)d_in[3];
  const float* conv1_b = (const float*)d_in[4];
  const float* sn_hw   = (const float*)d_in[5];
  const float* sn_ow   = (const float*)d_in[6];
  const float* sn_ob   = (const float*)d_in[7];
  const float* mats    = (const float*)d_in[8];
  const float* convt_w = (const float*)d_in[9];
  float* out = (float*)d_out;

  float* w = (float*)d_ws;
  float* xt = w + OFF_XT;
  float* sq = w + OFF_SQ;
  int* idx = (int*)(w + OFF_IDX);
  __hip_bfloat16* cvt_bf = (__hip_bfloat16*)(w + OFF_CVT);
  __hip_bfloat16* k2t_bf = (__hip_bfloat16*)(w + OFF_K2T);
  __hip_bfloat16* feats_bf = (__hip_bfloat16*)(w + OFF_FB);

  k_prep<<<704, 256, 0, stream>>>(x, convt_w, mats, xt, sq, cvt_bf, k2t_bf, out);
  k_knn<<<1024, 256, 0, stream>>>(xt, sq, idx);
  k_conv1<<<1024, 256, 0, stream>>>(xt, idx, conv1_w, conv1_b, feats_bf);
  for (int l = 0; l < 4; l++) {
    k_layer<<<256, 256, 0, stream>>>(xt, idx, sn_hw, sn_ow, sn_ob, k2t_bf, feats_bf, l);
  }
  k_final<<<512, 256, 0, stream>>>(feats_bf, cvt_bf, out);
}

// Round 8
// 194.773 us; speedup vs baseline: 2.1264x; 1.0681x over previous
//
#include <hip/hip_runtime.h>
#include <hip/hip_bf16.h>

// Problem constants
#define B 4
#define N 1024
#define KNN 30
#define MM 8
#define OUTC 512
#define HID 16
#define FD 320
#define BNS 0.9999950000374997f   // 1/sqrt(1+1e-5)

typedef float f32x4 __attribute__((ext_vector_type(4)));
typedef short s16x8 __attribute__((ext_vector_type(8)));

// workspace float offsets
#define OFF_XT     0          // 36864 floats
#define OFF_SQ     36864      // 4096
#define OFF_IDX    40960      // 122880 ints
#define OFF_CVT    163840     // convt bf16: 512*320
#define OFF_K2T    245760     // 4*64*1024 bf16
#define OFF_FB     376832     // feats bf16: 4096*320
#define OFF_SC     1032192    // score: 4*4096*240 floats = 3932160

// ---------------- prep (+ k2t transpose): one kernel, branch on blockIdx ----
__global__ void __launch_bounds__(256) k_prep(const float* __restrict__ x,
                                              const float* __restrict__ convt_w,
                                              const float* __restrict__ mats,
                                              float* __restrict__ xt,
                                              float* __restrict__ sq,
                                              __hip_bfloat16* __restrict__ cvt_bf,
                                              __hip_bfloat16* __restrict__ k2t_bf,
                                              float* __restrict__ out) {
  __shared__ float tile[64][65];
  if (blockIdx.x < 640) {
    int id = blockIdx.x * 256 + threadIdx.x;
    if (id < B * N) {
      int b = id >> 10, n = id & 1023;
      float s = 0.f;
#pragma unroll
      for (int c = 0; c < 9; c++) {
        float v = x[(b * 9 + c) * N + n];
        xt[id * 9 + c] = v;
        s = fmaf(v, v, s);
      }
      sq[id] = s;
    }
    if (id < B * OUTC) out[id] = 0.f;
    if (id < 512 * 320) cvt_bf[id] = __float2bfloat16(convt_w[id]);
  } else {
    int blk = blockIdx.x - 640;        // l*16 + part*8 + m  (64 blocks)
    int l = blk >> 4, part = (blk >> 3) & 1, m = blk & 7;
    int tr = threadIdx.x >> 6;         // 0..3
    int tc = threadIdx.x & 63;
    const float* src = mats + l * 65536 + (part * 64) * 512 + m * 64;
#pragma unroll
    for (int it = 0; it < 16; it++) {
      int c = it * 4 + tr;
      tile[c][tc] = src[c * 512 + tc];
    }
    __syncthreads();
    __hip_bfloat16* dst = k2t_bf + l * 65536 + part * 512 + m * 64;
#pragma unroll
    for (int it = 0; it < 16; it++) {
      int o = it * 4 + tr;
      dst[o * 1024 + tc] = __float2bfloat16(tile[tc][o]);
    }
  }
}

// ---------------- knn (radix select) + conv1 fused --------------------------
__global__ void __launch_bounds__(256) k_knnc1(const float* __restrict__ xt,
                                               const float* __restrict__ sq,
                                               const float* __restrict__ w,
                                               const float* __restrict__ bias,
                                               int* __restrict__ idx,
                                               __hip_bfloat16* __restrict__ feats_bf) {
  int t = threadIdx.x;
  int r = t >> 6;
  int lane = t & 63;
  int row = blockIdx.x * 4 + r;
  int b = row >> 10;
  __shared__ unsigned int hist[4][256];
  __shared__ unsigned int cntr[4];
  __shared__ unsigned int bp[4];
  __shared__ int bn[4];
  __shared__ int js_l[4][KNN];
  __shared__ float ws[64 * 18];
  __shared__ __align__(16) float diff_s[4][KNN][12];
  __shared__ float ctr_s[4][9];
  for (int i = t; i < 64 * 18; i += 256) ws[i] = w[i];
  if (t < 36) { int rr = t / 9, c = t - rr * 9; ctr_s[rr][c] = xt[(blockIdx.x * 4 + rr) * 9 + c]; }
  const float* xb = xt + (b << 10) * 9;
  const float* sb = sq + (b << 10);
  float cx[9];
#pragma unroll
  for (int c = 0; c < 9; c++) cx[c] = xt[row * 9 + c];
  float sqn = sq[row];
  unsigned int key[16];
#pragma unroll
  for (int s = 0; s < 16; s++) {
    int j = s * 64 + lane;
    const float* xj = xb + j * 9;
    float dot = 0.f;
#pragma unroll
    for (int c = 0; c < 9; c++) dot = fmaf(cx[c], xj[c], dot);
    float v = 2.0f * dot - sqn - sb[j];   // exactly 0 for j==n (same fmaf order)
    unsigned int u = __float_as_uint(v);
    key[s] = u ^ ((unsigned int)(((int)u) >> 31) | 0x80000000u);  // asc-sortable
  }
  if (lane == 0) cntr[r] = 0;
  unsigned int prefix = 0;
  int need = KNN;
  for (int p = 0; p < 4; p++) {
    int shift = 24 - 8 * p;
    for (int i = lane; i < 256; i += 64) hist[r][i] = 0;
    __syncthreads();
    unsigned int himask = (p == 0) ? 0u : (0xFFFFFFFFu << (shift + 8));
#pragma unroll
    for (int s = 0; s < 16; s++) {
      if ((key[s] & himask) == prefix)
        atomicAdd(&hist[r][(key[s] >> shift) & 255], 1u);
    }
    __syncthreads();
    int c0 = hist[r][4 * lane + 0], c1 = hist[r][4 * lane + 1];
    int c2 = hist[r][4 * lane + 2], c3 = hist[r][4 * lane + 3];
    int lsum = c0 + c1 + c2 + c3;
    int sfx = lsum;
#pragma unroll
    for (int ofs = 1; ofs < 64; ofs <<= 1) {
      int tt = __shfl_down(sfx, ofs, 64);
      if (lane + ofs < 64) sfx += tt;
    }
    int A3 = sfx - lsum;
    int A2 = A3 + c3, A1 = A2 + c2, A0 = A1 + c1;
    if (A0 < need && need <= A0 + c0) { bp[r] = prefix | ((unsigned)(4 * lane + 0) << shift); bn[r] = need - A0; }
    if (A1 < need && need <= A1 + c1) { bp[r] = prefix | ((unsigned)(4 * lane + 1) << shift); bn[r] = need - A1; }
    if (A2 < need && need <= A2 + c2) { bp[r] = prefix | ((unsigned)(4 * lane + 2) << shift); bn[r] = need - A2; }
    if (A3 < need && need <= A3 + c3) { bp[r] = prefix | ((unsigned)(4 * lane + 3) << shift); bn[r] = need - A3; }
    __syncthreads();
    prefix = bp[r];
    need = bn[r];
  }
  unsigned int T = prefix;
  int above_total = KNN - need;
  int* orow = idx + row * KNN;
#pragma unroll
  for (int s = 0; s < 16; s++) {
    if (key[s] > T) {
      unsigned int pslot = atomicAdd(&cntr[r], 1u);
      orow[pslot] = s * 64 + lane;
      js_l[r][pslot] = s * 64 + lane;
    }
  }
  int base = 0;
  for (int s = 0; s < 16; s++) {
    unsigned long long m = __ballot(key[s] == T);
    if (key[s] == T) {
      int rk = base + __popcll(m & ((1ull << lane) - 1ull));
      if (rk < need) {
        orow[above_total + rk] = s * 64 + lane;
        js_l[r][above_total + rk] = s * 64 + lane;
      }
    }
    base += __popcll(m);
    if (base >= need) break;
  }
  __syncthreads();
  // ---- conv1 phase ----
  if (t < 120) {
    int rr = t / KNN, k = t - rr * KNN;
    int j = js_l[rr][k];
    const float* xj = xt + ((b << 10) + j) * 9;
#pragma unroll
    for (int c = 0; c < 9; c++) diff_s[rr][k][c] = xj[c] - ctr_s[rr][c];
  }
  __syncthreads();
  float wd[9];
#pragma unroll
  for (int c = 0; c < 9; c++) wd[c] = ws[lane * 18 + c];
  float cd = 0.f;
#pragma unroll
  for (int c = 0; c < 9; c++) cd = fmaf(ctr_s[r][c], ws[lane * 18 + 9 + c], cd);
  float best = -3.0e38f;
  for (int k = 0; k < KNN; k++) {
    const float4* dr = (const float4*)diff_s[r][k];
    float4 d0 = dr[0], d1 = dr[1], d2v = dr[2];
    float dd = 0.f;
    dd = fmaf(d0.x, wd[0], dd); dd = fmaf(d0.y, wd[1], dd);
    dd = fmaf(d0.z, wd[2], dd); dd = fmaf(d0.w, wd[3], dd);
    dd = fmaf(d1.x, wd[4], dd); dd = fmaf(d1.y, wd[5], dd);
    dd = fmaf(d1.z, wd[6], dd); dd = fmaf(d1.w, wd[7], dd);
    dd = fmaf(d2v.x, wd[8], dd);
    best = fmaxf(best, dd);
  }
  float val = (best + cd + bias[lane]) * BNS;
  feats_bf[row * FD + lane] = __float2bfloat16(fmaxf(val, 0.f));
}

// ---------------- scorenet for ALL 4 layers: 1 thread per (row,k) -----------
__global__ void __launch_bounds__(256) k_score(const float* __restrict__ xt,
                                               const int* __restrict__ idx,
                                               const float* __restrict__ hw,
                                               const float* __restrict__ ow,
                                               const float* __restrict__ ob,
                                               float* __restrict__ score) {
  __shared__ float hws[4 * 448];
  __shared__ float ows[4 * 128];
  __shared__ float obs[32];
  int t = threadIdx.x;
  for (int i = t; i < 1792; i += 256) hws[i] = hw[i];
  for (int i = t; i < 512; i += 256) ows[i] = ow[i];
  if (t < 32) obs[t] = ob[t];
  __syncthreads();
  int id = blockIdx.x * 256 + t;       // 0..122879
  int row = id / KNN;
  int b = row >> 10;
  int j = idx[id];
  const float* xc = xt + row * 9;
  const float* xj = xt + ((b << 10) + j) * 9;
  float xv[28];
  float d2 = 0.f;
#pragma unroll
  for (int c = 0; c < 9; c++) {
    float nb = xj[c], ct = xc[c], df = nb - ct;
    xv[c] = df; xv[9 + c] = nb; xv[18 + c] = ct;
    d2 = fmaf(df, df, d2);
  }
  xv[27] = sqrtf(d2);
  for (int l = 0; l < 4; l++) {
    float hid[HID];
#pragma unroll
    for (int h = 0; h < HID; h++) {
      float a = 0.f;
#pragma unroll
      for (int c = 0; c < 28; c++) a = fmaf(xv[c], hws[l * 448 + h * 28 + c], a);
      hid[h] = fmaxf(a * BNS, 0.f);
    }
    float lg[MM], mx = -3.0e38f;
#pragma unroll
    for (int m = 0; m < MM; m++) {
      float a = obs[l * 8 + m];
#pragma unroll
      for (int h = 0; h < HID; h++) a = fmaf(hid[h], ows[l * 128 + m * 16 + h], a);
      lg[m] = a; mx = fmaxf(mx, a);
    }
    float s = 0.f;
#pragma unroll
    for (int m = 0; m < MM; m++) { lg[m] = __expf(lg[m] - mx); s += lg[m]; }
    float inv = 1.0f / s;
    float* so = score + l * 983040 + id * 8;
    *(float4*)so = make_float4(lg[0] * inv, lg[1] * inv, lg[2] * inv, lg[3] * inv);
    *(float4*)(so + 4) = make_float4(lg[4] * inv, lg[5] * inv, lg[6] * inv, lg[7] * inv);
  }
}

// ---------------- layer: g + (H @ K2) MFMA; last also folds final conv ------
__global__ void __launch_bounds__(512) k_layer2(const int* __restrict__ idx,
                                                const float* __restrict__ score,
                                                const __hip_bfloat16* __restrict__ k2t_bf,
                                                __hip_bfloat16* __restrict__ feats_bf,
                                                const __hip_bfloat16* __restrict__ cvt_bf,
                                                float* __restrict__ out,
                                                int l, int last) {
  int row0 = blockIdx.x * 16;
  int t = threadIdx.x;
  int b = row0 >> 10;
  __shared__ int js[16][KNN];
  __shared__ float ssum[16][8];
  __shared__ __align__(16) __hip_bfloat16 Hs[16][1040];     // 1024 + 16 pad
  __shared__ __align__(16) __hip_bfloat16 ftile[16][336];   // last-layer A tile
  const float* sc_l = score + l * 983040;
  for (int i = t; i < 16 * KNN; i += 512) {
    int r = i / KNN, k = i - r * KNN;
    js[r][k] = (b << 10) + idx[(row0 + r) * KNN + k];
  }
  if (t < 128) {
    int r = t >> 3, m = t & 7;
    float a = 0.f;
    for (int k = 0; k < KNN; k++) a += sc_l[(row0 + r) * 240 + k * 8 + m];
    ssum[r][m] = a;
  }
  __syncthreads();
  int wv = t >> 6, lane = t & 63;
#pragma unroll
  for (int rr = 0; rr < 2; rr++) {
    int r = wv * 2 + rr;
    int row = row0 + r;
    const float4* srow = (const float4*)(sc_l + row * 240);
    float g[MM] = {};
#pragma unroll
    for (int k = 0; k < KNN; k++) {
      float fv = __bfloat162float(feats_bf[js[r][k] * FD + l * 64 + lane]);
      float4 s0 = srow[2 * k], s1 = srow[2 * k + 1];
      g[0] = fmaf(s0.x, fv, g[0]); g[1] = fmaf(s0.y, fv, g[1]);
      g[2] = fmaf(s0.z, fv, g[2]); g[3] = fmaf(s0.w, fv, g[3]);
      g[4] = fmaf(s1.x, fv, g[4]); g[5] = fmaf(s1.y, fv, g[5]);
      g[6] = fmaf(s1.z, fv, g[6]); g[7] = fmaf(s1.w, fv, g[7]);
    }
    float fn = __bfloat162float(feats_bf[row * FD + l * 64 + lane]);
#pragma unroll
    for (int m = 0; m < MM; m++) {
      Hs[r][m * 64 + lane] = __float2bfloat16(g[m] - ssum[r][m] * fn);
      Hs[r][512 + m * 64 + lane] = __float2bfloat16(g[m]);
    }
  }
  __syncthreads();
  int lr = lane & 15, lk8 = (lane >> 4) * 8;
  if (wv < 4) {
    const short* Ks2 = (const short*)(k2t_bf + l * 65536);
    const short* brow = Ks2 + (wv * 16 + lr) * 1024 + lk8;
    const short* arow = (const short*)&Hs[lr][lk8];
    f32x4 acc = {0.f, 0.f, 0.f, 0.f};
#pragma unroll 8
    for (int kk = 0; kk < 32; kk++) {
      s16x8 a = *(const s16x8*)(arow + kk * 32);
      s16x8 bb = *(const s16x8*)(brow + kk * 32);
      acc = __builtin_amdgcn_mfma_f32_16x16x32_bf16(a, bb, acc, 0, 0, 0);
    }
    if (!last) {
#pragma unroll
      for (int i = 0; i < 4; i++) {
        int row = row0 + (lane >> 4) * 4 + i;
        feats_bf[row * FD + (l + 1) * 64 + wv * 16 + lr] =
            __float2bfloat16(fmaxf(acc[i] * BNS, 0.f));
      }
    } else {
#pragma unroll
      for (int i = 0; i < 4; i++) {
        int rl = (lane >> 4) * 4 + i;
        ftile[rl][256 + wv * 16 + lr] = __float2bfloat16(fmaxf(acc[i] * BNS, 0.f));
      }
    }
  } else if (last) {
    // waves 4..7: stage cols 0..255 of our 16 rows into ftile (runs in parallel
    // with waves 0..3's H-GEMM)
    int t2 = t - 256;   // 0..255
    const short* Fs = (const short*)feats_bf;
    for (int i = t2; i < 512; i += 256) {
      int r = i >> 5, c8 = (i & 31) * 8;
      *(s16x8*)&ftile[r][c8] = *(const s16x8*)(Fs + (row0 + r) * FD + c8);
    }
  }
  if (last) {
    __syncthreads();
    const short* Ws = (const short*)cvt_bf;
#pragma unroll
    for (int tn = 0; tn < 4; tn++) {
      int nb = wv * 64 + tn * 16;
      const short* brow = Ws + (nb + lr) * FD + lk8;
      f32x4 acc = {0.f, 0.f, 0.f, 0.f};
#pragma unroll
      for (int kk = 0; kk < 10; kk++) {
        s16x8 a = *(const s16x8*)&ftile[lr][kk * 32 + lk8];
        s16x8 bb = *(const s16x8*)(brow + kk * 32);
        acc = __builtin_amdgcn_mfma_f32_16x16x32_bf16(a, bb, acc, 0, 0, 0);
      }
      float mx = fmaxf(fmaxf(acc[0], acc[1]), fmaxf(acc[2], acc[3]));
      mx = fmaxf(mx, __shfl_xor(mx, 16, 64));
      mx = fmaxf(mx, __shfl_xor(mx, 32, 64));
      if ((lane >> 4) == 0) {
        float val = fmaxf(mx * BNS, 0.f);
        atomicMax((unsigned int*)out + b * OUTC + nb + lr, __float_as_uint(val));
      }
    }
  }
}

extern "C" void kernel_launch(void* const* d_in, const int* in_sizes, int n_in,
                              void* d_out, int out_size, void* d_ws, size_t ws_size,
                              hipStream_t stream) {
  const float* x       = (const float*)d_in[0];
  const float* conv1_w = (const float*)d_in[3];
  const float* conv1_b = (const float*)d_in[4];
  const float* sn_hw   = (const float*)d_in[5];
  const float* sn_ow   = (const float*)d_in[6];
  const float* sn_ob   = (const float*)d_in[7];
  const float* mats    = (const float*)d_in[8];
  const float* convt_w = (const float*)d_in[9];
  float* out = (float*)d_out;

  float* w = (float*)d_ws;
  float* xt = w + OFF_XT;
  float* sq = w + OFF_SQ;
  int* idx = (int*)(w + OFF_IDX);
  __hip_bfloat16* cvt_bf = (__hip_bfloat16*)(w + OFF_CVT);
  __hip_bfloat16* k2t_bf = (__hip_bfloat16*)(w + OFF_K2T);
  __hip_bfloat16* feats_bf = (__hip_bfloat16*)(w + OFF_FB);
  float* score = w + OFF_SC;

  k_prep<<<704, 256, 0, stream>>>(x, convt_w, mats, xt, sq, cvt_bf, k2t_bf, out);
  k_knnc1<<<1024, 256, 0, stream>>>(xt, sq, conv1_w, conv1_b, idx, feats_bf);
  k_score<<<480, 256, 0, stream>>>(xt, idx, sn_hw, sn_ow, sn_ob, score);
  for (int l = 0; l < 4; l++) {
    k_layer2<<<256, 512, 0, stream>>>(idx, score, k2t_bf, feats_bf, cvt_bf, out,
                                      l, l == 3 ? 1 : 0);
  }
}